// Round 1
// baseline (537.873 us; speedup 1.0000x reference)
//
#include <hip/hip_runtime.h>

#define NN 65536
#define NE 1048576
#define INDIM 512
#define HID 128

// ---------------- degree / dinv ----------------
__global__ void k_init_deg_cnt(float* deg, int* cnt) {
    int i = blockIdx.x * 256 + threadIdx.x;
    if (i < NN) { deg[i] = 1.0f; cnt[i] = 0; }
}

__global__ void k_deg_edges(const int* __restrict__ dst, const float* __restrict__ ew,
                            float* deg, int* cnt) {
    int e = blockIdx.x * 256 + threadIdx.x;
    if (e < NE) {
        int d = dst[e];
        atomicAdd(&deg[d], ew[e]);
        atomicAdd(&cnt[d], 1);
    }
}

__global__ void k_make_dinv(float* deg) {
    int i = blockIdx.x * 256 + threadIdx.x;
    if (i < NN) {
        float d = deg[i];
        deg[i] = (d > 0.f) ? rsqrtf(d) : 0.f;
    }
}

// ---------------- CSR build: scan + scatter ----------------
__global__ void k_scan_block(const int* __restrict__ cnt, int* row_ptr, int* bsum) {
    __shared__ int tmp[256];
    int i = blockIdx.x * 256 + threadIdx.x;
    int v = cnt[i];
    tmp[threadIdx.x] = v;
    __syncthreads();
    for (int off = 1; off < 256; off <<= 1) {
        int t = (threadIdx.x >= off) ? tmp[threadIdx.x - off] : 0;
        __syncthreads();
        tmp[threadIdx.x] += t;
        __syncthreads();
    }
    row_ptr[i] = tmp[threadIdx.x] - v;   // exclusive
    if (threadIdx.x == 255) bsum[blockIdx.x] = tmp[255];
}

__global__ void k_scan_bsum(int* bsum) {
    __shared__ int tmp[256];
    int v = bsum[threadIdx.x];
    tmp[threadIdx.x] = v;
    __syncthreads();
    for (int off = 1; off < 256; off <<= 1) {
        int t = (threadIdx.x >= off) ? tmp[threadIdx.x - off] : 0;
        __syncthreads();
        tmp[threadIdx.x] += t;
        __syncthreads();
    }
    bsum[threadIdx.x] = tmp[threadIdx.x] - v; // exclusive block offsets
}

__global__ void k_scan_add(int* row_ptr, const int* __restrict__ bsum, int* pos) {
    int i = blockIdx.x * 256 + threadIdx.x;
    row_ptr[i] += bsum[blockIdx.x];
    pos[i] = 0;
    if (i == 0) row_ptr[NN] = NE;
}

__global__ void k_scatter(const int* __restrict__ src, const int* __restrict__ dst,
                          const float* __restrict__ ew, const float* __restrict__ dinv,
                          const int* __restrict__ row_ptr, int* pos,
                          int* s_src, float* s_coef) {
    int e = blockIdx.x * 256 + threadIdx.x;
    if (e < NE) {
        int d = dst[e], s = src[e];
        int p = row_ptr[d] + atomicAdd(&pos[d], 1);
        s_src[p] = s;
        s_coef[p] = dinv[s] * ew[e] * dinv[d];
    }
}

// ---------------- f32 tiled GEMM: C[M,128] = A[M,K] @ B[K,128] ----------------
template <int K>
__global__ __launch_bounds__(256) void k_gemm_f32(const float* __restrict__ A,
                                                  const float* __restrict__ B,
                                                  float* __restrict__ C) {
    constexpr int BM = 128, BN = 128, BK = 16;
    __shared__ __align__(16) float As[BK][132];  // transposed: As[k][m], padded
    __shared__ __align__(16) float Bs[BK][BN];
    const int tid = threadIdx.x;
    const int cx = tid & 15;   // col group: 8 cols each
    const int ry = tid >> 4;   // row group: 8 rows each
    const int m0 = blockIdx.x * BM;

    float acc[8][8];
#pragma unroll
    for (int i = 0; i < 8; i++)
#pragma unroll
        for (int j = 0; j < 8; j++) acc[i][j] = 0.f;

    for (int k0 = 0; k0 < K; k0 += BK) {
        // A tile: 128 x 16 (2 float4 per thread), store transposed
#pragma unroll
        for (int l = 0; l < 2; l++) {
            int idx4 = tid + l * 256;
            int row = idx4 >> 2;
            int cg = idx4 & 3;
            float4 v = *(const float4*)(A + (size_t)(m0 + row) * K + k0 + cg * 4);
            As[cg * 4 + 0][row] = v.x;
            As[cg * 4 + 1][row] = v.y;
            As[cg * 4 + 2][row] = v.z;
            As[cg * 4 + 3][row] = v.w;
        }
        // B tile: 16 x 128 (2 float4 per thread)
#pragma unroll
        for (int l = 0; l < 2; l++) {
            int idx4 = tid + l * 256;
            int row = idx4 >> 5;
            int c4 = idx4 & 31;
            *(float4*)(&Bs[row][c4 * 4]) = *(const float4*)(B + (size_t)(k0 + row) * BN + c4 * 4);
        }
        __syncthreads();
#pragma unroll
        for (int kk = 0; kk < BK; kk++) {
            float a[8], b[8];
            *(float4*)&a[0] = *(const float4*)&As[kk][ry * 8];
            *(float4*)&a[4] = *(const float4*)&As[kk][ry * 8 + 4];
            *(float4*)&b[0] = *(const float4*)&Bs[kk][cx * 8];
            *(float4*)&b[4] = *(const float4*)&Bs[kk][cx * 8 + 4];
#pragma unroll
            for (int i = 0; i < 8; i++)
#pragma unroll
                for (int j = 0; j < 8; j++) acc[i][j] += a[i] * b[j];
        }
        __syncthreads();
    }
#pragma unroll
    for (int i = 0; i < 8; i++) {
        float4 v0 = make_float4(acc[i][0], acc[i][1], acc[i][2], acc[i][3]);
        float4 v1 = make_float4(acc[i][4], acc[i][5], acc[i][6], acc[i][7]);
        float* crow = C + (size_t)(m0 + ry * 8 + i) * BN + cx * 8;
        *(float4*)crow = v0;
        *(float4*)(crow + 4) = v1;
    }
}

// ---------------- aggregation: out[d] = sum coef*h[s] + dinv[d]^2 h[d] + b ----------------
template <bool RELU>
__global__ __launch_bounds__(256) void k_agg(const float* __restrict__ h,
                                             const float* __restrict__ dinv,
                                             const int* __restrict__ row_ptr,
                                             const int* __restrict__ s_src,
                                             const float* __restrict__ s_coef,
                                             const float* __restrict__ bias,
                                             float* __restrict__ out) {
    int d = (blockIdx.x * blockDim.x + threadIdx.x) >> 6;  // one wave per node
    int lane = threadIdx.x & 63;
    if (d >= NN) return;
    float di = dinv[d];
    float selfc = di * di;
    float2 hv = ((const float2*)(h + (size_t)d * HID))[lane];
    float ax = selfc * hv.x, ay = selfc * hv.y;
    int beg = row_ptr[d], end = row_ptr[d + 1];
    for (int e = beg; e < end; ++e) {
        int s = s_src[e];
        float c = s_coef[e];
        float2 v = ((const float2*)(h + (size_t)s * HID))[lane];
        ax += c * v.x;
        ay += c * v.y;
    }
    float2 bv = ((const float2*)bias)[lane];
    ax += bv.x;
    ay += bv.y;
    if (RELU) {
        ax = fmaxf(ax, 0.f);
        ay = fmaxf(ay, 0.f);
    }
    float2 r;
    r.x = ax;
    r.y = ay;
    ((float2*)(out + (size_t)d * HID))[lane] = r;
}

extern "C" void kernel_launch(void* const* d_in, const int* in_sizes, int n_in,
                              void* d_out, int out_size, void* d_ws, size_t ws_size,
                              hipStream_t stream) {
    const float* x = (const float*)d_in[0];
    const int* ei = (const int*)d_in[1];
    const float* ew = (const float*)d_in[2];
    const float* W1 = (const float*)d_in[3];
    const float* b1 = (const float*)d_in[4];
    const float* W2 = (const float*)d_in[5];
    const float* b2 = (const float*)d_in[6];
    const int* src = ei;
    const int* dst = ei + NE;
    float* out = (float*)d_out;

    char* ws = (char*)d_ws;
    float* dinv    = (float*)(ws + 0);        // 64K f32
    int*   row_ptr = (int*)(ws + 262144);     // 64K+1 int
    int*   pos     = (int*)(ws + 524544);     // 64K int (doubles as cnt)
    int*   bsum    = (int*)(ws + 786688);     // 256 int
    int*   s_src   = (int*)(ws + 787712);     // 1M int
    float* s_coef  = (float*)(ws + 4982016);  // 1M f32
    float* h       = (float*)(ws + 9176320);  // 8M f32 (65536 x 128)

    // degrees + CSR (built once, used by both layers)
    k_init_deg_cnt<<<NN / 256, 256, 0, stream>>>(dinv, pos);
    k_deg_edges<<<NE / 256, 256, 0, stream>>>(dst, ew, dinv, pos);
    k_make_dinv<<<NN / 256, 256, 0, stream>>>(dinv);
    k_scan_block<<<256, 256, 0, stream>>>(pos, row_ptr, bsum);
    k_scan_bsum<<<1, 256, 0, stream>>>(bsum);
    k_scan_add<<<256, 256, 0, stream>>>(row_ptr, bsum, pos);
    k_scatter<<<NE / 256, 256, 0, stream>>>(src, dst, ew, dinv, row_ptr, pos, s_src, s_coef);

    // layer 1: h = x @ W1 ; a1 = relu(agg(h) + b1) -> d_out
    k_gemm_f32<INDIM><<<NN / 128, 256, 0, stream>>>(x, W1, h);
    k_agg<true><<<NN / 4, 256, 0, stream>>>(h, dinv, row_ptr, s_src, s_coef, b1, out);

    // layer 2: h2 = a1 @ W2 -> h ; z = agg(h2) + b2 -> d_out
    k_gemm_f32<HID><<<NN / 128, 256, 0, stream>>>(out, W2, h);
    k_agg<false><<<NN / 4, 256, 0, stream>>>(h, dinv, row_ptr, s_src, s_coef, b2, out);
}

// Round 2
// 440.719 us; speedup vs baseline: 1.2204x; 1.2204x over previous
//
#include <hip/hip_runtime.h>

#define NN 65536
#define NE 1048576
#define INDIM 512
#define HID 128

typedef __attribute__((ext_vector_type(8))) short bf16x8;
typedef __attribute__((ext_vector_type(16))) float f32x16;

// ---------------- degree / dinv ----------------
__global__ void k_init_deg_cnt(float* deg, int* cnt) {
    int i = blockIdx.x * 256 + threadIdx.x;
    if (i < NN) { deg[i] = 1.0f; cnt[i] = 0; }
}

__global__ void k_deg_edges(const int* __restrict__ dst, const float* __restrict__ ew,
                            float* deg, int* cnt) {
    int e = blockIdx.x * 256 + threadIdx.x;
    if (e < NE) {
        int d = dst[e];
        atomicAdd(&deg[d], ew[e]);
        atomicAdd(&cnt[d], 1);
    }
}

__global__ void k_make_dinv(float* deg) {
    int i = blockIdx.x * 256 + threadIdx.x;
    if (i < NN) {
        float d = deg[i];
        deg[i] = (d > 0.f) ? rsqrtf(d) : 0.f;
    }
}

// ---------------- CSR build: scan + scatter ----------------
__global__ void k_scan_block(const int* __restrict__ cnt, int* row_ptr, int* bsum) {
    __shared__ int tmp[256];
    int i = blockIdx.x * 256 + threadIdx.x;
    int v = cnt[i];
    tmp[threadIdx.x] = v;
    __syncthreads();
    for (int off = 1; off < 256; off <<= 1) {
        int t = (threadIdx.x >= off) ? tmp[threadIdx.x - off] : 0;
        __syncthreads();
        tmp[threadIdx.x] += t;
        __syncthreads();
    }
    row_ptr[i] = tmp[threadIdx.x] - v;   // exclusive
    if (threadIdx.x == 255) bsum[blockIdx.x] = tmp[255];
}

__global__ void k_scan_bsum(int* bsum) {
    __shared__ int tmp[256];
    int v = bsum[threadIdx.x];
    tmp[threadIdx.x] = v;
    __syncthreads();
    for (int off = 1; off < 256; off <<= 1) {
        int t = (threadIdx.x >= off) ? tmp[threadIdx.x - off] : 0;
        __syncthreads();
        tmp[threadIdx.x] += t;
        __syncthreads();
    }
    bsum[threadIdx.x] = tmp[threadIdx.x] - v; // exclusive block offsets
}

__global__ void k_scan_add(int* row_ptr, const int* __restrict__ bsum, int* pos) {
    int i = blockIdx.x * 256 + threadIdx.x;
    row_ptr[i] += bsum[blockIdx.x];
    pos[i] = 0;
    if (i == 0) row_ptr[NN] = NE;
}

__global__ void k_scatter(const int* __restrict__ src, const int* __restrict__ dst,
                          const float* __restrict__ ew, const float* __restrict__ dinv,
                          const int* __restrict__ row_ptr, int* pos,
                          int* s_src, float* s_coef) {
    int e = blockIdx.x * 256 + threadIdx.x;
    if (e < NE) {
        int d = dst[e], s = src[e];
        int p = row_ptr[d] + atomicAdd(&pos[d], 1);
        s_src[p] = s;
        s_coef[p] = dinv[s] * ew[e] * dinv[d];
    }
}

// ---------------- W prep: f32 [K][128] -> transposed split-bf16 [128][K] ----------------
template <int K>
__global__ void k_prep_w(const float* __restrict__ W,
                         unsigned short* __restrict__ hi, unsigned short* __restrict__ lo) {
    int i = blockIdx.x * 256 + threadIdx.x;
    if (i < K * 128) {
        int k = i >> 7, n = i & 127;
        float f = W[i];
        unsigned b = __float_as_uint(f);
        unsigned hb = b & 0xFFFF0000u;
        float lf = f - __uint_as_float(hb);
        hi[n * K + k] = (unsigned short)(hb >> 16);
        lo[n * K + k] = (unsigned short)(__float_as_uint(lf) >> 16);
    }
}

// ---------------- split-bf16 MFMA GEMM: C[M,128] = A[M,K] @ W[K,128] ----------------
__device__ __forceinline__ void split8(const float4& a0, const float4& a1,
                                       bf16x8& hi, bf16x8& lo) {
    float f[8] = {a0.x, a0.y, a0.z, a0.w, a1.x, a1.y, a1.z, a1.w};
#pragma unroll
    for (int i = 0; i < 8; i++) {
        unsigned b = __float_as_uint(f[i]);
        unsigned hb = b & 0xFFFF0000u;
        float lf = f[i] - __uint_as_float(hb);
        hi[i] = (short)(hb >> 16);
        lo[i] = (short)(__float_as_uint(lf) >> 16);
    }
}

template <int K>
__global__ __launch_bounds__(256) void k_gemm_mfma(const float* __restrict__ A,
                                                   const unsigned short* __restrict__ Whi,
                                                   const unsigned short* __restrict__ Wlo,
                                                   float* __restrict__ C) {
    const int tid = threadIdx.x;
    const int wave = tid >> 6;
    const int lane = tid & 63;
    const int l31 = lane & 31;
    const int lhalf = lane >> 5;
    const int row = blockIdx.x * 128 + wave * 32 + l31;
    const float* arow = A + (size_t)row * K;

    f32x16 acc[4] = {};

    for (int k0 = 0; k0 < K; k0 += 16) {
        const int kf = k0 + lhalf * 8;
        float4 a0 = *(const float4*)(arow + kf);
        float4 a1 = *(const float4*)(arow + kf + 4);
        bf16x8 ahi, alo;
        split8(a0, a1, ahi, alo);
#pragma unroll
        for (int n = 0; n < 4; n++) {
            const int col = n * 32 + l31;
            bf16x8 bhi = *(const bf16x8*)(Whi + (size_t)col * K + kf);
            bf16x8 blo = *(const bf16x8*)(Wlo + (size_t)col * K + kf);
            acc[n] = __builtin_amdgcn_mfma_f32_32x32x16_bf16(ahi, bhi, acc[n], 0, 0, 0);
            acc[n] = __builtin_amdgcn_mfma_f32_32x32x16_bf16(ahi, blo, acc[n], 0, 0, 0);
            acc[n] = __builtin_amdgcn_mfma_f32_32x32x16_bf16(alo, bhi, acc[n], 0, 0, 0);
        }
    }

    const int rbase = blockIdx.x * 128 + wave * 32 + 4 * lhalf;
#pragma unroll
    for (int n = 0; n < 4; n++) {
        const int col = n * 32 + l31;
#pragma unroll
        for (int r = 0; r < 16; r++) {
            int rout = rbase + (r & 3) + 8 * (r >> 2);
            C[(size_t)rout * HID + col] = acc[n][r];
        }
    }
}

// ---------------- aggregation: out[d] = sum coef*h[s] + dinv[d]^2 h[d] + b ----------------
template <bool RELU>
__global__ __launch_bounds__(256) void k_agg(const float* __restrict__ h,
                                             const float* __restrict__ dinv,
                                             const int* __restrict__ row_ptr,
                                             const int* __restrict__ s_src,
                                             const float* __restrict__ s_coef,
                                             const float* __restrict__ bias,
                                             float* __restrict__ out) {
    int d = (blockIdx.x * blockDim.x + threadIdx.x) >> 6;  // one wave per node
    int lane = threadIdx.x & 63;
    if (d >= NN) return;
    float di = dinv[d];
    float selfc = di * di;
    float2 hv = ((const float2*)(h + (size_t)d * HID))[lane];
    float ax = selfc * hv.x, ay = selfc * hv.y;
    int beg = row_ptr[d], end = row_ptr[d + 1];
    int e = beg;
    for (; e + 1 < end; e += 2) {
        int s0 = s_src[e], s1 = s_src[e + 1];
        float c0 = s_coef[e], c1 = s_coef[e + 1];
        float2 v0 = ((const float2*)(h + (size_t)s0 * HID))[lane];
        float2 v1 = ((const float2*)(h + (size_t)s1 * HID))[lane];
        ax += c0 * v0.x; ay += c0 * v0.y;
        ax += c1 * v1.x; ay += c1 * v1.y;
    }
    if (e < end) {
        int s = s_src[e];
        float c = s_coef[e];
        float2 v = ((const float2*)(h + (size_t)s * HID))[lane];
        ax += c * v.x; ay += c * v.y;
    }
    float2 bv = ((const float2*)bias)[lane];
    ax += bv.x;
    ay += bv.y;
    if (RELU) {
        ax = fmaxf(ax, 0.f);
        ay = fmaxf(ay, 0.f);
    }
    float2 r;
    r.x = ax;
    r.y = ay;
    ((float2*)(out + (size_t)d * HID))[lane] = r;
}

extern "C" void kernel_launch(void* const* d_in, const int* in_sizes, int n_in,
                              void* d_out, int out_size, void* d_ws, size_t ws_size,
                              hipStream_t stream) {
    const float* x = (const float*)d_in[0];
    const int* ei = (const int*)d_in[1];
    const float* ew = (const float*)d_in[2];
    const float* W1 = (const float*)d_in[3];
    const float* b1 = (const float*)d_in[4];
    const float* W2 = (const float*)d_in[5];
    const float* b2 = (const float*)d_in[6];
    const int* src = ei;
    const int* dst = ei + NE;
    float* out = (float*)d_out;

    char* ws = (char*)d_ws;
    float* dinv    = (float*)(ws + 0);         // 64K f32
    int*   row_ptr = (int*)(ws + 262144);      // 64K+1 int
    int*   pos     = (int*)(ws + 524544);      // 64K int (doubles as cnt)
    int*   bsum    = (int*)(ws + 786688);      // 256 int
    int*   s_src   = (int*)(ws + 787712);      // 1M int
    float* s_coef  = (float*)(ws + 4982016);   // 1M f32
    float* h       = (float*)(ws + 9176320);   // 8M f32 (65536 x 128)
    unsigned short* w1hi = (unsigned short*)(ws + 42730752);  // 128x512 bf16
    unsigned short* w1lo = (unsigned short*)(ws + 42861824);
    unsigned short* w2hi = (unsigned short*)(ws + 42992896);  // 128x128 bf16
    unsigned short* w2lo = (unsigned short*)(ws + 43025664);

    // degrees + CSR (built once, used by both layers) + weight prep
    k_init_deg_cnt<<<NN / 256, 256, 0, stream>>>(dinv, pos);
    k_deg_edges<<<NE / 256, 256, 0, stream>>>(dst, ew, dinv, pos);
    k_make_dinv<<<NN / 256, 256, 0, stream>>>(dinv);
    k_scan_block<<<256, 256, 0, stream>>>(pos, row_ptr, bsum);
    k_scan_bsum<<<1, 256, 0, stream>>>(bsum);
    k_scan_add<<<256, 256, 0, stream>>>(row_ptr, bsum, pos);
    k_scatter<<<NE / 256, 256, 0, stream>>>(src, dst, ew, dinv, row_ptr, pos, s_src, s_coef);
    k_prep_w<INDIM><<<INDIM * 128 / 256, 256, 0, stream>>>(W1, w1hi, w1lo);
    k_prep_w<HID><<<HID * 128 / 256, 256, 0, stream>>>(W2, w2hi, w2lo);

    // layer 1: h = x @ W1 ; a1 = relu(agg(h) + b1) -> d_out
    k_gemm_mfma<INDIM><<<NN / 128, 256, 0, stream>>>(x, w1hi, w1lo, h);
    k_agg<true><<<NN / 4, 256, 0, stream>>>(h, dinv, row_ptr, s_src, s_coef, b1, out);

    // layer 2: h2 = a1 @ W2 -> h ; z = agg(h2) + b2 -> d_out
    k_gemm_mfma<HID><<<NN / 128, 256, 0, stream>>>(out, w2hi, w2lo, h);
    k_agg<false><<<NN / 4, 256, 0, stream>>>(h, dinv, row_ptr, s_src, s_coef, b2, out);
}

// Round 3
// 407.768 us; speedup vs baseline: 1.3191x; 1.0808x over previous
//
#include <hip/hip_runtime.h>

#define NN 65536
#define NE 1048576
#define INDIM 512
#define HID 128

typedef __attribute__((ext_vector_type(8))) short bf16x8;
typedef __attribute__((ext_vector_type(16))) float f32x16;

// ---------------- degree / dinv ----------------
__global__ void k_init_deg_cnt(float* deg, int* cnt) {
    int i = blockIdx.x * 256 + threadIdx.x;
    if (i < NN) { deg[i] = 1.0f; cnt[i] = 0; }
}

__global__ void k_deg_edges(const int* __restrict__ dst, const float* __restrict__ ew,
                            float* deg, int* cnt) {
    int e = blockIdx.x * 256 + threadIdx.x;
    if (e < NE) {
        int d = dst[e];
        atomicAdd(&deg[d], ew[e]);
        atomicAdd(&cnt[d], 1);
    }
}

__global__ void k_make_dinv(float* deg) {
    int i = blockIdx.x * 256 + threadIdx.x;
    if (i < NN) {
        float d = deg[i];
        deg[i] = (d > 0.f) ? rsqrtf(d) : 0.f;
    }
}

// ---------------- CSR build: scan + scatter ----------------
__global__ void k_scan_block(const int* __restrict__ cnt, int* row_ptr, int* bsum) {
    __shared__ int tmp[256];
    int i = blockIdx.x * 256 + threadIdx.x;
    int v = cnt[i];
    tmp[threadIdx.x] = v;
    __syncthreads();
    for (int off = 1; off < 256; off <<= 1) {
        int t = (threadIdx.x >= off) ? tmp[threadIdx.x - off] : 0;
        __syncthreads();
        tmp[threadIdx.x] += t;
        __syncthreads();
    }
    row_ptr[i] = tmp[threadIdx.x] - v;   // exclusive
    if (threadIdx.x == 255) bsum[blockIdx.x] = tmp[255];
}

__global__ void k_scan_bsum(int* bsum) {
    __shared__ int tmp[256];
    int v = bsum[threadIdx.x];
    tmp[threadIdx.x] = v;
    __syncthreads();
    for (int off = 1; off < 256; off <<= 1) {
        int t = (threadIdx.x >= off) ? tmp[threadIdx.x - off] : 0;
        __syncthreads();
        tmp[threadIdx.x] += t;
        __syncthreads();
    }
    bsum[threadIdx.x] = tmp[threadIdx.x] - v; // exclusive block offsets
}

__global__ void k_scan_add(int* row_ptr, const int* __restrict__ bsum, int* pos) {
    int i = blockIdx.x * 256 + threadIdx.x;
    row_ptr[i] += bsum[blockIdx.x];
    pos[i] = 0;
    if (i == 0) row_ptr[NN] = NE;
}

__global__ void k_scatter(const int* __restrict__ src, const int* __restrict__ dst,
                          const float* __restrict__ ew, const float* __restrict__ dinv,
                          const int* __restrict__ row_ptr, int* pos,
                          int* s_src, float* s_coef) {
    int e = blockIdx.x * 256 + threadIdx.x;
    if (e < NE) {
        int d = dst[e], s = src[e];
        int p = row_ptr[d] + atomicAdd(&pos[d], 1);
        s_src[p] = s;
        s_coef[p] = dinv[s] * ew[e] * dinv[d];
    }
}

// ---------------- W prep: f32 [K][128] -> MFMA-fragment-packed split-bf16 ----------------
// Layout: P[(((k0*4 + n)*2 + h)*64 + lane)*8 + j]  (16B fragment per lane, coalesced)
// fragment element j = split(W[k0*16 + (lane>>5)*8 + j][n*32 + (lane&31)]).{hi,lo}
template <int K>
__global__ void k_prep_pack(const float* __restrict__ W, unsigned short* __restrict__ P) {
    int t = blockIdx.x * 256 + threadIdx.x;
    int l = t & 63;
    int h = (t >> 6) & 1;
    int n = (t >> 7) & 3;
    int k0 = t >> 9;
    if (k0 >= K / 16) return;
    int colg = n * 32 + (l & 31);
    int kbase = k0 * 16 + (l >> 5) * 8;
    bf16x8 v;
#pragma unroll
    for (int j = 0; j < 8; j++) {
        float f = W[(size_t)(kbase + j) * 128 + colg];
        unsigned b = __float_as_uint(f);
        if (h == 0) {
            v[j] = (short)(b >> 16);
        } else {
            float lf = f - __uint_as_float(b & 0xFFFF0000u);
            v[j] = (short)(__float_as_uint(lf) >> 16);
        }
    }
    *(bf16x8*)(P + (size_t)t * 8) = v;
}

// ---------------- split-bf16 MFMA GEMM: C[M,128] = A[M,K] @ W[K,128] ----------------
__device__ __forceinline__ void split8(const float4& a0, const float4& a1,
                                       bf16x8& hi, bf16x8& lo) {
    float f[8] = {a0.x, a0.y, a0.z, a0.w, a1.x, a1.y, a1.z, a1.w};
#pragma unroll
    for (int i = 0; i < 8; i++) {
        unsigned b = __float_as_uint(f[i]);
        unsigned hb = b & 0xFFFF0000u;
        float lf = f[i] - __uint_as_float(hb);
        hi[i] = (short)(hb >> 16);
        lo[i] = (short)(__float_as_uint(lf) >> 16);
    }
}

// wave tile: 32 rows x 64 cols. block = 256 threads = 4 waves = 64 rows x 128 cols.
// A prefetch depth 3 (registers), B double-buffered (registers), no LDS, no barriers.
template <int K>
__global__ __launch_bounds__(256, 4) void k_gemm_mfma(const float* __restrict__ A,
                                                      const unsigned short* __restrict__ Bp,
                                                      float* __restrict__ C) {
    constexpr int NIT = K / 16;
    constexpr int PF = 3;
    const int tid = threadIdx.x;
    const int w = tid >> 6;
    const int lane = tid & 63;
    const int l31 = lane & 31;
    const int lhalf = lane >> 5;
    const int row = blockIdx.x * 64 + (w >> 1) * 32 + l31;
    const int ncol = (w & 1) * 2;  // which pair of 32-col tiles
    const float* arow = A + (size_t)row * K + lhalf * 8;

    f32x16 acc[2] = {};

    float4 abuf[PF][2];
#pragma unroll
    for (int p = 0; p < PF; p++) {
        abuf[p][0] = *(const float4*)(arow + p * 16);
        abuf[p][1] = *(const float4*)(arow + p * 16 + 4);
    }

    bf16x8 bbuf[2][2][2];  // [buf][n][hi/lo]
#pragma unroll
    for (int n = 0; n < 2; n++)
#pragma unroll
        for (int h = 0; h < 2; h++)
            bbuf[0][n][h] = *(const bf16x8*)(Bp + ((size_t)((ncol + n) * 2 + h) * 64 + lane) * 8);

#pragma unroll
    for (int it = 0; it < NIT; it++) {
        // consume current A into split registers first (frees abuf slot for WAR reuse)
        bf16x8 ahi, alo;
        split8(abuf[it % PF][0], abuf[it % PF][1], ahi, alo);
        // issue A prefetch for it+PF
        if (it + PF < NIT) {
            abuf[it % PF][0] = *(const float4*)(arow + (it + PF) * 16);
            abuf[it % PF][1] = *(const float4*)(arow + (it + PF) * 16 + 4);
        }
        // issue B prefetch for it+1
        if (it + 1 < NIT) {
#pragma unroll
            for (int n = 0; n < 2; n++)
#pragma unroll
                for (int h = 0; h < 2; h++)
                    bbuf[(it + 1) & 1][n][h] =
                        *(const bf16x8*)(Bp + ((size_t)(((it + 1) * 4 + ncol + n) * 2 + h) * 64 + lane) * 8);
        }
#pragma unroll
        for (int n = 0; n < 2; n++) {
            acc[n] = __builtin_amdgcn_mfma_f32_32x32x16_bf16(ahi, bbuf[it & 1][n][0], acc[n], 0, 0, 0);
            acc[n] = __builtin_amdgcn_mfma_f32_32x32x16_bf16(ahi, bbuf[it & 1][n][1], acc[n], 0, 0, 0);
            acc[n] = __builtin_amdgcn_mfma_f32_32x32x16_bf16(alo, bbuf[it & 1][n][0], acc[n], 0, 0, 0);
        }
    }

    const int rbase = blockIdx.x * 64 + (w >> 1) * 32 + 4 * lhalf;
#pragma unroll
    for (int n = 0; n < 2; n++) {
        const int col = (ncol + n) * 32 + l31;
#pragma unroll
        for (int r = 0; r < 16; r++) {
            int rout = rbase + (r & 3) + 8 * (r >> 2);
            C[(size_t)rout * HID + col] = acc[n][r];
        }
    }
}

// ---------------- aggregation: out[d] = sum coef*h[s] + dinv[d]^2 h[d] + b ----------------
template <bool RELU>
__global__ __launch_bounds__(256) void k_agg(const float* __restrict__ h,
                                             const float* __restrict__ dinv,
                                             const int* __restrict__ row_ptr,
                                             const int* __restrict__ s_src,
                                             const float* __restrict__ s_coef,
                                             const float* __restrict__ bias,
                                             float* __restrict__ out) {
    int d = (blockIdx.x * blockDim.x + threadIdx.x) >> 6;  // one wave per node
    int lane = threadIdx.x & 63;
    if (d >= NN) return;
    float di = dinv[d];
    float selfc = di * di;
    float2 hv = ((const float2*)(h + (size_t)d * HID))[lane];
    float ax = selfc * hv.x, ay = selfc * hv.y;
    int beg = row_ptr[d], end = row_ptr[d + 1];
    int e = beg;
    for (; e + 1 < end; e += 2) {
        int s0 = s_src[e], s1 = s_src[e + 1];
        float c0 = s_coef[e], c1 = s_coef[e + 1];
        float2 v0 = ((const float2*)(h + (size_t)s0 * HID))[lane];
        float2 v1 = ((const float2*)(h + (size_t)s1 * HID))[lane];
        ax += c0 * v0.x; ay += c0 * v0.y;
        ax += c1 * v1.x; ay += c1 * v1.y;
    }
    if (e < end) {
        int s = s_src[e];
        float c = s_coef[e];
        float2 v = ((const float2*)(h + (size_t)s * HID))[lane];
        ax += c * v.x; ay += c * v.y;
    }
    float2 bv = ((const float2*)bias)[lane];
    ax += bv.x;
    ay += bv.y;
    if (RELU) {
        ax = fmaxf(ax, 0.f);
        ay = fmaxf(ay, 0.f);
    }
    float2 r;
    r.x = ax;
    r.y = ay;
    ((float2*)(out + (size_t)d * HID))[lane] = r;
}

extern "C" void kernel_launch(void* const* d_in, const int* in_sizes, int n_in,
                              void* d_out, int out_size, void* d_ws, size_t ws_size,
                              hipStream_t stream) {
    const float* x = (const float*)d_in[0];
    const int* ei = (const int*)d_in[1];
    const float* ew = (const float*)d_in[2];
    const float* W1 = (const float*)d_in[3];
    const float* b1 = (const float*)d_in[4];
    const float* W2 = (const float*)d_in[5];
    const float* b2 = (const float*)d_in[6];
    const int* src = ei;
    const int* dst = ei + NE;
    float* out = (float*)d_out;

    char* ws = (char*)d_ws;
    float* dinv    = (float*)(ws + 0);         // 64K f32
    int*   row_ptr = (int*)(ws + 262144);      // 64K+1 int
    int*   pos     = (int*)(ws + 524544);      // 64K int (doubles as cnt)
    int*   bsum    = (int*)(ws + 786688);      // 256 int
    int*   s_src   = (int*)(ws + 787712);      // 1M int
    float* s_coef  = (float*)(ws + 4982016);   // 1M f32
    float* h       = (float*)(ws + 9176320);   // 8M f32 (65536 x 128)
    unsigned short* bp1 = (unsigned short*)(ws + 42730752);  // 256KB packed W1
    unsigned short* bp2 = (unsigned short*)(ws + 42992896);  // 64KB packed W2

    // degrees + CSR (built once, used by both layers) + weight prep
    k_init_deg_cnt<<<NN / 256, 256, 0, stream>>>(dinv, pos);
    k_deg_edges<<<NE / 256, 256, 0, stream>>>(dst, ew, dinv, pos);
    k_make_dinv<<<NN / 256, 256, 0, stream>>>(dinv);
    k_scan_block<<<256, 256, 0, stream>>>(pos, row_ptr, bsum);
    k_scan_bsum<<<1, 256, 0, stream>>>(bsum);
    k_scan_add<<<256, 256, 0, stream>>>(row_ptr, bsum, pos);
    k_scatter<<<NE / 256, 256, 0, stream>>>(src, dst, ew, dinv, row_ptr, pos, s_src, s_coef);
    k_prep_pack<INDIM><<<(INDIM / 16) * 8 * 64 / 256, 256, 0, stream>>>(W1, bp1);
    k_prep_pack<HID><<<(HID / 16) * 8 * 64 / 256, 256, 0, stream>>>(W2, bp2);

    // layer 1: h = x @ W1 ; a1 = relu(agg(h) + b1) -> d_out
    k_gemm_mfma<INDIM><<<NN / 64, 256, 0, stream>>>(x, bp1, h);
    k_agg<true><<<NN / 4, 256, 0, stream>>>(h, dinv, row_ptr, s_src, s_coef, b1, out);

    // layer 2: h2 = a1 @ W2 -> h ; z = agg(h2) + b2 -> d_out
    k_gemm_mfma<HID><<<NN / 64, 256, 0, stream>>>(out, bp2, h);
    k_agg<false><<<NN / 4, 256, 0, stream>>>(h, dinv, row_ptr, s_src, s_coef, b2, out);
}

// Round 5
// 378.963 us; speedup vs baseline: 1.4193x; 1.0760x over previous
//
#include <hip/hip_runtime.h>

#define NN 65536
#define NE 1048576
#define INDIM 512
#define HID 128
#define NREP 8

typedef __attribute__((ext_vector_type(8))) short bf16x8;
typedef __attribute__((ext_vector_type(16))) float f32x16;

// ---------------- zero the replicated histogram ----------------
__global__ void k_zero_cnt(int* pos_rep) {
    int i = blockIdx.x * 256 + threadIdx.x;
    pos_rep[i] = 0;  // grid sized exactly NREP*NN
}

// ---------------- replicated int histogram over dst (into pos_rep) ----------------
__global__ void k_hist(const int* __restrict__ dst, int* pos_rep) {
    int e = blockIdx.x * 256 + threadIdx.x;
    int r = blockIdx.x & (NREP - 1);
    if (e < NE) atomicAdd(&pos_rep[r * NN + dst[e]], 1);
}

// ---------------- per-node replica prefix (in place) + totals ----------------
__global__ void k_rowptr_pre(int* pos_rep, int* tot) {
    int i = blockIdx.x * 256 + threadIdx.x;  // node
    int s = 0;
#pragma unroll
    for (int r = 0; r < NREP; r++) {
        int c = pos_rep[r * NN + i];
        pos_rep[r * NN + i] = s;  // relative offset within node segment
        s += c;
    }
    tot[i] = s;
}

// ---------------- two-level exclusive scan of tot -> row_ptr ----------------
__global__ void k_scan_block(const int* __restrict__ tot, int* row_ptr, int* bsum) {
    __shared__ int tmp[256];
    int i = blockIdx.x * 256 + threadIdx.x;
    int v = tot[i];
    tmp[threadIdx.x] = v;
    __syncthreads();
    for (int off = 1; off < 256; off <<= 1) {
        int t = (threadIdx.x >= off) ? tmp[threadIdx.x - off] : 0;
        __syncthreads();
        tmp[threadIdx.x] += t;
        __syncthreads();
    }
    row_ptr[i] = tmp[threadIdx.x] - v;   // exclusive
    if (threadIdx.x == 255) bsum[blockIdx.x] = tmp[255];
}

__global__ void k_scan_bsum(int* bsum) {
    __shared__ int tmp[256];
    int v = bsum[threadIdx.x];
    tmp[threadIdx.x] = v;
    __syncthreads();
    for (int off = 1; off < 256; off <<= 1) {
        int t = (threadIdx.x >= off) ? tmp[threadIdx.x - off] : 0;
        __syncthreads();
        tmp[threadIdx.x] += t;
        __syncthreads();
    }
    bsum[threadIdx.x] = tmp[threadIdx.x] - v; // exclusive block offsets
}

__global__ void k_scan_add(int* row_ptr, const int* __restrict__ bsum, int* pos_rep) {
    int i = blockIdx.x * 256 + threadIdx.x;
    int rp = row_ptr[i] + bsum[blockIdx.x];
    row_ptr[i] = rp;
#pragma unroll
    for (int r = 0; r < NREP; r++) pos_rep[r * NN + i] += rp;  // absolute cursors
    if (i == 0) row_ptr[NN] = NE;
}

// ---------------- scatter edges into dst-sorted order ----------------
__global__ void k_scatter(const int* __restrict__ src, const int* __restrict__ dst,
                          const float* __restrict__ ew,
                          int* pos_rep, uint2* __restrict__ edata) {
    int e = blockIdx.x * 256 + threadIdx.x;
    int r = blockIdx.x & (NREP - 1);
    if (e < NE) {
        int d = dst[e];
        int p = atomicAdd(&pos_rep[r * NN + d], 1);
        uint2 u;
        u.x = (unsigned)src[e];
        u.y = __float_as_uint(ew[e]);
        edata[p] = u;
    }
}

// ---------------- deg from CSR (no atomics) + dinv ----------------
__global__ void k_deg_dinv(const int* __restrict__ row_ptr, const uint2* __restrict__ edata,
                           float* __restrict__ dinv) {
    int d = blockIdx.x * 256 + threadIdx.x;  // one thread per node
    int beg = row_ptr[d], end = row_ptr[d + 1];
    float deg = 1.0f;  // self-loop weight
    for (int e = beg; e < end; ++e) deg += __uint_as_float(edata[e].y);
    dinv[d] = (deg > 0.f) ? rsqrtf(deg) : 0.f;
}

// ---------------- fold dinv[src] into edge weight ----------------
__global__ void k_coef(const float* __restrict__ dinv, uint2* edata) {
    int e = blockIdx.x * 256 + threadIdx.x;
    if (e < NE) {
        uint2 u = edata[e];
        float c = dinv[u.x] * __uint_as_float(u.y);
        u.y = __float_as_uint(c);
        edata[e] = u;
    }
}

// ---------------- W prep: f32 [K][128] -> MFMA-fragment-packed split-bf16 ----------------
// Layout: P[(((k0*4 + n)*2 + h)*64 + lane)*8 + j]
template <int K>
__global__ void k_prep_pack(const float* __restrict__ W, unsigned short* __restrict__ P) {
    int t = blockIdx.x * 256 + threadIdx.x;
    int l = t & 63;
    int h = (t >> 6) & 1;
    int n = (t >> 7) & 3;
    int k0 = t >> 9;
    if (k0 >= K / 16) return;
    int colg = n * 32 + (l & 31);
    int kbase = k0 * 16 + (l >> 5) * 8;
    bf16x8 v;
#pragma unroll
    for (int j = 0; j < 8; j++) {
        float f = W[(size_t)(kbase + j) * 128 + colg];
        unsigned b = __float_as_uint(f);
        if (h == 0) {
            v[j] = (short)(b >> 16);
        } else {
            float lf = f - __uint_as_float(b & 0xFFFF0000u);
            v[j] = (short)(__float_as_uint(lf) >> 16);
        }
    }
    *(bf16x8*)(P + (size_t)t * 8) = v;
}

// ---------------- split-bf16 MFMA GEMM: C[M,128] = A[M,K] @ W[K,128] ----------------
__device__ __forceinline__ void split8(const float4& a0, const float4& a1,
                                       bf16x8& hi, bf16x8& lo) {
    float f[8] = {a0.x, a0.y, a0.z, a0.w, a1.x, a1.y, a1.z, a1.w};
#pragma unroll
    for (int i = 0; i < 8; i++) {
        unsigned b = __float_as_uint(f[i]);
        unsigned hb = b & 0xFFFF0000u;
        float lf = f[i] - __uint_as_float(hb);
        hi[i] = (short)(hb >> 16);
        lo[i] = (short)(__float_as_uint(lf) >> 16);
    }
}

template <int K>
__global__ __launch_bounds__(256, 4) void k_gemm_mfma(const float* __restrict__ A,
                                                      const unsigned short* __restrict__ Bp,
                                                      float* __restrict__ C) {
    constexpr int NIT = K / 16;
    constexpr int PF = 3;
    const int tid = threadIdx.x;
    const int w = tid >> 6;
    const int lane = tid & 63;
    const int l31 = lane & 31;
    const int lhalf = lane >> 5;
    const int row = blockIdx.x * 64 + (w >> 1) * 32 + l31;
    const int ncol = (w & 1) * 2;
    const float* arow = A + (size_t)row * K + lhalf * 8;

    f32x16 acc[2] = {};

    float4 abuf[PF][2];
#pragma unroll
    for (int p = 0; p < PF; p++) {
        abuf[p][0] = *(const float4*)(arow + p * 16);
        abuf[p][1] = *(const float4*)(arow + p * 16 + 4);
    }

    bf16x8 bbuf[2][2][2];
#pragma unroll
    for (int n = 0; n < 2; n++)
#pragma unroll
        for (int h = 0; h < 2; h++)
            bbuf[0][n][h] = *(const bf16x8*)(Bp + ((size_t)((ncol + n) * 2 + h) * 64 + lane) * 8);

#pragma unroll
    for (int it = 0; it < NIT; it++) {
        bf16x8 ahi, alo;
        split8(abuf[it % PF][0], abuf[it % PF][1], ahi, alo);
        if (it + PF < NIT) {
            abuf[it % PF][0] = *(const float4*)(arow + (it + PF) * 16);
            abuf[it % PF][1] = *(const float4*)(arow + (it + PF) * 16 + 4);
        }
        if (it + 1 < NIT) {
#pragma unroll
            for (int n = 0; n < 2; n++)
#pragma unroll
                for (int h = 0; h < 2; h++)
                    bbuf[(it + 1) & 1][n][h] =
                        *(const bf16x8*)(Bp + ((size_t)(((it + 1) * 4 + ncol + n) * 2 + h) * 64 + lane) * 8);
        }
#pragma unroll
        for (int n = 0; n < 2; n++) {
            acc[n] = __builtin_amdgcn_mfma_f32_32x32x16_bf16(ahi, bbuf[it & 1][n][0], acc[n], 0, 0, 0);
            acc[n] = __builtin_amdgcn_mfma_f32_32x32x16_bf16(ahi, bbuf[it & 1][n][1], acc[n], 0, 0, 0);
            acc[n] = __builtin_amdgcn_mfma_f32_32x32x16_bf16(alo, bbuf[it & 1][n][0], acc[n], 0, 0, 0);
        }
    }

    const int rbase = blockIdx.x * 64 + (w >> 1) * 32 + 4 * lhalf;
#pragma unroll
    for (int n = 0; n < 2; n++) {
        const int col = (ncol + n) * 32 + l31;
#pragma unroll
        for (int r = 0; r < 16; r++) {
            int rout = rbase + (r & 3) + 8 * (r >> 2);
            C[(size_t)rout * HID + col] = acc[n][r];
        }
    }
}

// ---------------- aggregation: out[d] = di*(sum c*h[s]) + di^2*h[d] + b ----------------
template <bool RELU>
__global__ __launch_bounds__(256) void k_agg(const float* __restrict__ h,
                                             const float* __restrict__ dinv,
                                             const int* __restrict__ row_ptr,
                                             const uint2* __restrict__ edata,
                                             const float* __restrict__ bias,
                                             float* __restrict__ out) {
    int d = (blockIdx.x * blockDim.x + threadIdx.x) >> 6;  // one wave per node
    int lane = threadIdx.x & 63;
    if (d >= NN) return;
    float di = dinv[d];
    float2 hv = ((const float2*)(h + (size_t)d * HID))[lane];
    int beg = row_ptr[d], end = row_ptr[d + 1];
    float ex = 0.f, ey = 0.f;
    int e = beg;
    for (; e + 3 < end; e += 4) {
        uint2 u0 = edata[e], u1 = edata[e + 1], u2 = edata[e + 2], u3 = edata[e + 3];
        float2 v0 = ((const float2*)(h + (size_t)u0.x * HID))[lane];
        float2 v1 = ((const float2*)(h + (size_t)u1.x * HID))[lane];
        float2 v2 = ((const float2*)(h + (size_t)u2.x * HID))[lane];
        float2 v3 = ((const float2*)(h + (size_t)u3.x * HID))[lane];
        float c0 = __uint_as_float(u0.y), c1 = __uint_as_float(u1.y);
        float c2 = __uint_as_float(u2.y), c3 = __uint_as_float(u3.y);
        ex += c0 * v0.x; ey += c0 * v0.y;
        ex += c1 * v1.x; ey += c1 * v1.y;
        ex += c2 * v2.x; ey += c2 * v2.y;
        ex += c3 * v3.x; ey += c3 * v3.y;
    }
    for (; e < end; ++e) {
        uint2 u = edata[e];
        float2 v = ((const float2*)(h + (size_t)u.x * HID))[lane];
        float c = __uint_as_float(u.y);
        ex += c * v.x; ey += c * v.y;
    }
    float2 bv = ((const float2*)bias)[lane];
    float selfc = di * di;
    float ax = di * ex + selfc * hv.x + bv.x;
    float ay = di * ey + selfc * hv.y + bv.y;
    if (RELU) {
        ax = fmaxf(ax, 0.f);
        ay = fmaxf(ay, 0.f);
    }
    float2 rr;
    rr.x = ax;
    rr.y = ay;
    ((float2*)(out + (size_t)d * HID))[lane] = rr;
}

extern "C" void kernel_launch(void* const* d_in, const int* in_sizes, int n_in,
                              void* d_out, int out_size, void* d_ws, size_t ws_size,
                              hipStream_t stream) {
    const float* x = (const float*)d_in[0];
    const int* ei = (const int*)d_in[1];
    const float* ew = (const float*)d_in[2];
    const float* W1 = (const float*)d_in[3];
    const float* b1 = (const float*)d_in[4];
    const float* W2 = (const float*)d_in[5];
    const float* b2 = (const float*)d_in[6];
    const int* src = ei;
    const int* dst = ei + NE;
    float* out = (float*)d_out;

    // Workspace layout (lifetime-aliased; high-water mark 42,795,136 B):
    //   h       @ 0          32 MB  persistent (first written by gemm1)
    //     pos_rep aliases h[0..2MB] — dead after k_scatter, before gemm1
    //   edata   @ 33,554,432  8 MB  persistent (first written by k_scatter)
    //     tot  aliases edata[0..256KB]   — dead before k_scatter
    //     bsum aliases edata[256KB..+1KB] — dead before k_scatter
    //   row_ptr @ 41,943,040  (64K+1 ints, persistent)
    //   dinv    @ 42,205,312  (256 KB, persistent)
    //   bp1     @ 42,467,456  (256 KB, persistent)
    //   bp2     @ 42,729,600  ( 64 KB, persistent)
    char* ws = (char*)d_ws;
    float* h       = (float*)(ws + 0);
    int*   pos_rep = (int*)(ws + 0);
    uint2* edata   = (uint2*)(ws + 33554432);
    int*   tot     = (int*)(ws + 33554432);
    int*   bsum    = (int*)(ws + 33816576);
    int*   row_ptr = (int*)(ws + 41943040);
    float* dinv    = (float*)(ws + 42205312);
    unsigned short* bp1 = (unsigned short*)(ws + 42467456);
    unsigned short* bp2 = (unsigned short*)(ws + 42729600);

    // CSR build (atomic-light): replicated hist -> scan -> scatter -> deg/dinv -> coef
    k_zero_cnt<<<NREP * NN / 256, 256, 0, stream>>>(pos_rep);
    k_hist<<<NE / 256, 256, 0, stream>>>(dst, pos_rep);
    k_rowptr_pre<<<NN / 256, 256, 0, stream>>>(pos_rep, tot);
    k_scan_block<<<256, 256, 0, stream>>>(tot, row_ptr, bsum);
    k_scan_bsum<<<1, 256, 0, stream>>>(bsum);
    k_scan_add<<<256, 256, 0, stream>>>(row_ptr, bsum, pos_rep);
    k_scatter<<<NE / 256, 256, 0, stream>>>(src, dst, ew, pos_rep, edata);
    k_deg_dinv<<<NN / 256, 256, 0, stream>>>(row_ptr, edata, dinv);
    k_coef<<<NE / 256, 256, 0, stream>>>(dinv, edata);
    k_prep_pack<INDIM><<<(INDIM / 16) * 8 * 64 / 256, 256, 0, stream>>>(W1, bp1);
    k_prep_pack<HID><<<(HID / 16) * 8 * 64 / 256, 256, 0, stream>>>(W2, bp2);

    // layer 1: h = x @ W1 ; a1 = relu(agg(h) + b1) -> d_out
    k_gemm_mfma<INDIM><<<NN / 64, 256, 0, stream>>>(x, bp1, h);
    k_agg<true><<<NN / 4, 256, 0, stream>>>(h, dinv, row_ptr, edata, b1, out);

    // layer 2: h2 = a1 @ W2 -> h ; z = agg(h2) + b2 -> d_out
    k_gemm_mfma<HID><<<NN / 64, 256, 0, stream>>>(out, bp2, h);
    k_agg<false><<<NN / 4, 256, 0, stream>>>(h, dinv, row_ptr, edata, b2, out);
}

// Round 6
// 361.999 us; speedup vs baseline: 1.4858x; 1.0469x over previous
//
#include <hip/hip_runtime.h>

#define NN 65536
#define NE 1048576
#define INDIM 512
#define HID 128
#define NREP 8

typedef __attribute__((ext_vector_type(8))) short bf16x8;
typedef __attribute__((ext_vector_type(16))) float f32x16;

// ---------------- zero the replicated histogram ----------------
__global__ void k_zero_cnt(int* pos_rep) {
    int i = blockIdx.x * 256 + threadIdx.x;
    pos_rep[i] = 0;  // grid sized exactly NREP*NN
}

// ---------------- replicated int histogram over dst (into pos_rep) ----------------
__global__ void k_hist(const int* __restrict__ dst, int* pos_rep) {
    int e = blockIdx.x * 256 + threadIdx.x;
    int r = blockIdx.x & (NREP - 1);
    if (e < NE) atomicAdd(&pos_rep[r * NN + dst[e]], 1);
}

// ---------------- per-node replica prefix (in place) + totals ----------------
__global__ void k_rowptr_pre(int* pos_rep, int* tot) {
    int i = blockIdx.x * 256 + threadIdx.x;  // node
    int s = 0;
#pragma unroll
    for (int r = 0; r < NREP; r++) {
        int c = pos_rep[r * NN + i];
        pos_rep[r * NN + i] = s;  // relative offset within node segment
        s += c;
    }
    tot[i] = s;
}

// ---------------- two-level exclusive scan of tot -> row_ptr ----------------
__global__ void k_scan_block(const int* __restrict__ tot, int* row_ptr, int* bsum) {
    __shared__ int tmp[256];
    int i = blockIdx.x * 256 + threadIdx.x;
    int v = tot[i];
    tmp[threadIdx.x] = v;
    __syncthreads();
    for (int off = 1; off < 256; off <<= 1) {
        int t = (threadIdx.x >= off) ? tmp[threadIdx.x - off] : 0;
        __syncthreads();
        tmp[threadIdx.x] += t;
        __syncthreads();
    }
    row_ptr[i] = tmp[threadIdx.x] - v;   // exclusive
    if (threadIdx.x == 255) bsum[blockIdx.x] = tmp[255];
}

__global__ void k_scan_bsum(int* bsum) {
    __shared__ int tmp[256];
    int v = bsum[threadIdx.x];
    tmp[threadIdx.x] = v;
    __syncthreads();
    for (int off = 1; off < 256; off <<= 1) {
        int t = (threadIdx.x >= off) ? tmp[threadIdx.x - off] : 0;
        __syncthreads();
        tmp[threadIdx.x] += t;
        __syncthreads();
    }
    bsum[threadIdx.x] = tmp[threadIdx.x] - v; // exclusive block offsets
}

__global__ void k_scan_add(int* row_ptr, const int* __restrict__ bsum, int* pos_rep) {
    int i = blockIdx.x * 256 + threadIdx.x;
    int rp = row_ptr[i] + bsum[blockIdx.x];
    row_ptr[i] = rp;
#pragma unroll
    for (int r = 0; r < NREP; r++) pos_rep[r * NN + i] += rp;  // absolute cursors
    if (i == 0) row_ptr[NN] = NE;
}

// ---------------- scatter edges into dst-sorted order ----------------
__global__ void k_scatter(const int* __restrict__ src, const int* __restrict__ dst,
                          const float* __restrict__ ew,
                          int* pos_rep, uint2* __restrict__ edata) {
    int e = blockIdx.x * 256 + threadIdx.x;
    int r = blockIdx.x & (NREP - 1);
    if (e < NE) {
        int d = dst[e];
        int p = atomicAdd(&pos_rep[r * NN + d], 1);
        uint2 u;
        u.x = (unsigned)src[e];
        u.y = __float_as_uint(ew[e]);
        edata[p] = u;
    }
}

// ---------------- deg from CSR (no atomics) + dinv ----------------
__global__ void k_deg_dinv(const int* __restrict__ row_ptr, const uint2* __restrict__ edata,
                           float* __restrict__ dinv) {
    int d = blockIdx.x * 256 + threadIdx.x;  // one thread per node
    int beg = row_ptr[d], end = row_ptr[d + 1];
    float deg = 1.0f;  // self-loop weight
    for (int e = beg; e < end; ++e) deg += __uint_as_float(edata[e].y);
    dinv[d] = (deg > 0.f) ? rsqrtf(deg) : 0.f;
}

// ---------------- fold dinv[src] into edge weight ----------------
__global__ void k_coef(const float* __restrict__ dinv, uint2* edata) {
    int e = blockIdx.x * 256 + threadIdx.x;
    if (e < NE) {
        uint2 u = edata[e];
        float c = dinv[u.x] * __uint_as_float(u.y);
        u.y = __float_as_uint(c);
        edata[e] = u;
    }
}

// ---------------- W prep: f32 [K][128] -> MFMA-fragment-packed split-bf16 ----------------
// Layout: P[(((k0*4 + n)*2 + h)*64 + lane)*8 + j]  (16B granule per lane-fragment)
template <int K>
__global__ void k_prep_pack(const float* __restrict__ W, unsigned short* __restrict__ P) {
    int t = blockIdx.x * 256 + threadIdx.x;
    int l = t & 63;
    int h = (t >> 6) & 1;
    int n = (t >> 7) & 3;
    int k0 = t >> 9;
    if (k0 >= K / 16) return;
    int colg = n * 32 + (l & 31);
    int kbase = k0 * 16 + (l >> 5) * 8;
    bf16x8 v;
#pragma unroll
    for (int j = 0; j < 8; j++) {
        float f = W[(size_t)(kbase + j) * 128 + colg];
        unsigned b = __float_as_uint(f);
        if (h == 0) {
            v[j] = (short)(b >> 16);
        } else {
            float lf = f - __uint_as_float(b & 0xFFFF0000u);
            v[j] = (short)(__float_as_uint(lf) >> 16);
        }
    }
    *(bf16x8*)(P + (size_t)t * 8) = v;
}

// ---------------- split-bf16 MFMA GEMM: C[M,128] = A[M,K] @ W[K,128] ----------------
__device__ __forceinline__ void split8(const float4& a0, const float4& a1,
                                       bf16x8& hi, bf16x8& lo) {
    float f[8] = {a0.x, a0.y, a0.z, a0.w, a1.x, a1.y, a1.z, a1.w};
#pragma unroll
    for (int i = 0; i < 8; i++) {
        unsigned b = __float_as_uint(f[i]);
        unsigned hb = b & 0xFFFF0000u;
        float lf = f[i] - __uint_as_float(hb);
        hi[i] = (short)(hb >> 16);
        lo[i] = (short)(__float_as_uint(lf) >> 16);
    }
}

// Stage one BK=32 chunk into LDS via global_load_lds (width 16, linear dest).
// A LDS layout (8KB): granule pos = ((kk*2 + lhalf)*64 + row)*2 + g_stored,
//   g_stored = g_logical ^ ((row>>2)&1)  [bank spread], content = A[row][c*32 + kk*16 + lhalf*8 + g*4 ..+4]
// B LDS layout (16KB): identity copy of Bp chunk (already fragment-packed).
template <int K>
__device__ __forceinline__ void stage_chunk(const float* __restrict__ A, int rowbase,
                                            const unsigned short* __restrict__ Bp,
                                            int c, int tid, float* As, unsigned short* Bs) {
    const int w = tid >> 6;
    // A: 8KB = 2 calls x 256 threads x 16B
#pragma unroll
    for (int q = 0; q < 2; ++q) {
        int lh = (tid >> 7) & 1;
        int row = (tid >> 1) & 63;
        int g = (tid & 1) ^ ((row >> 2) & 1);
        const float* src = A + (size_t)(rowbase + row) * K + c * 32 + q * 16 + lh * 8 + g * 4;
        char* dst = (char*)As + (size_t)(q * 256 + w * 64) * 16;
        __builtin_amdgcn_global_load_lds((const __attribute__((address_space(1))) void*)src,
                                         (__attribute__((address_space(3))) void*)dst, 16, 0, 0);
    }
    // B: 16KB = 4 calls (identity copy)
    const char* bsrc0 = (const char*)Bp + (size_t)c * 16384;
#pragma unroll
    for (int q = 0; q < 4; ++q) {
        const char* src = bsrc0 + (size_t)(q * 256 + tid) * 16;
        char* dst = (char*)Bs + (size_t)(q * 256 + w * 64) * 16;
        __builtin_amdgcn_global_load_lds((const __attribute__((address_space(1))) void*)src,
                                         (__attribute__((address_space(3))) void*)dst, 16, 0, 0);
    }
}

// Block: 64 rows x 128 cols, 4 waves (2 row-groups x 2 col-groups), wave tile 32x64.
template <int K>
__global__ __launch_bounds__(256, 4) void k_gemm_mfma(const float* __restrict__ A,
                                                      const unsigned short* __restrict__ Bp,
                                                      float* __restrict__ C) {
    constexpr int NC = K / 32;
    __shared__ __align__(16) float As[2048];            // 8KB
    __shared__ __align__(16) unsigned short Bs[8192];   // 16KB
    const int tid = threadIdx.x;
    const int w = tid >> 6;
    const int lane = tid & 63;
    const int l31 = lane & 31;
    const int lhalf = lane >> 5;
    const int rowbase = blockIdx.x * 64;
    const int ncol = (w & 1) * 2;          // col-group: tiles ncol, ncol+1
    const int r = (w >> 1) * 32 + l31;     // row within 64-row tile
    const int xr = (l31 >> 2) & 1;

    f32x16 acc[2] = {};

    stage_chunk<K>(A, rowbase, Bp, 0, tid, As, Bs);

    for (int c = 0; c < NC; ++c) {
        __syncthreads();  // staged chunk visible (compiler drains vmcnt before barrier)
#pragma unroll
        for (int kk = 0; kk < 2; ++kk) {
            int bg = ((kk * 2 + lhalf) * 64 + r) * 2;
            float4 aa = *(const float4*)&As[(size_t)(bg + xr) * 4];        // k+0..3
            float4 ab = *(const float4*)&As[(size_t)(bg + (1 ^ xr)) * 4];  // k+4..7
            bf16x8 ahi, alo;
            split8(aa, ab, ahi, alo);
#pragma unroll
            for (int n = 0; n < 2; ++n) {
                int f = (ncol + n) * 2;
                bf16x8 bhi = *(const bf16x8*)&Bs[(size_t)((kk * 8 + f) * 64 + lane) * 8];
                bf16x8 blo = *(const bf16x8*)&Bs[(size_t)((kk * 8 + f + 1) * 64 + lane) * 8];
                acc[n] = __builtin_amdgcn_mfma_f32_32x32x16_bf16(ahi, bhi, acc[n], 0, 0, 0);
                acc[n] = __builtin_amdgcn_mfma_f32_32x32x16_bf16(ahi, blo, acc[n], 0, 0, 0);
                acc[n] = __builtin_amdgcn_mfma_f32_32x32x16_bf16(alo, bhi, acc[n], 0, 0, 0);
            }
        }
        __syncthreads();  // all waves done reading before restaging
        if (c + 1 < NC) stage_chunk<K>(A, rowbase, Bp, c + 1, tid, As, Bs);
    }

    const int rbase = rowbase + (w >> 1) * 32 + 4 * lhalf;
#pragma unroll
    for (int n = 0; n < 2; ++n) {
        const int col = (ncol + n) * 32 + l31;
#pragma unroll
        for (int rr = 0; rr < 16; ++rr) {
            int rout = rbase + (rr & 3) + 8 * (rr >> 2);
            C[(size_t)rout * HID + col] = acc[n][rr];
        }
    }
}

// ---------------- aggregation: out[d] = di*(sum c*h[s]) + di^2*h[d] + b ----------------
template <bool RELU>
__global__ __launch_bounds__(256) void k_agg(const float* __restrict__ h,
                                             const float* __restrict__ dinv,
                                             const int* __restrict__ row_ptr,
                                             const uint2* __restrict__ edata,
                                             const float* __restrict__ bias,
                                             float* __restrict__ out) {
    int d = (blockIdx.x * blockDim.x + threadIdx.x) >> 6;  // one wave per node
    int lane = threadIdx.x & 63;
    if (d >= NN) return;
    float di = dinv[d];
    float2 hv = ((const float2*)(h + (size_t)d * HID))[lane];
    int beg = row_ptr[d], end = row_ptr[d + 1];
    float ex = 0.f, ey = 0.f;
    int e = beg;
    for (; e + 3 < end; e += 4) {
        uint2 u0 = edata[e], u1 = edata[e + 1], u2 = edata[e + 2], u3 = edata[e + 3];
        float2 v0 = ((const float2*)(h + (size_t)u0.x * HID))[lane];
        float2 v1 = ((const float2*)(h + (size_t)u1.x * HID))[lane];
        float2 v2 = ((const float2*)(h + (size_t)u2.x * HID))[lane];
        float2 v3 = ((const float2*)(h + (size_t)u3.x * HID))[lane];
        float c0 = __uint_as_float(u0.y), c1 = __uint_as_float(u1.y);
        float c2 = __uint_as_float(u2.y), c3 = __uint_as_float(u3.y);
        ex += c0 * v0.x; ey += c0 * v0.y;
        ex += c1 * v1.x; ey += c1 * v1.y;
        ex += c2 * v2.x; ey += c2 * v2.y;
        ex += c3 * v3.x; ey += c3 * v3.y;
    }
    for (; e < end; ++e) {
        uint2 u = edata[e];
        float2 v = ((const float2*)(h + (size_t)u.x * HID))[lane];
        float c = __uint_as_float(u.y);
        ex += c * v.x; ey += c * v.y;
    }
    float2 bv = ((const float2*)bias)[lane];
    float selfc = di * di;
    float ax = di * ex + selfc * hv.x + bv.x;
    float ay = di * ey + selfc * hv.y + bv.y;
    if (RELU) {
        ax = fmaxf(ax, 0.f);
        ay = fmaxf(ay, 0.f);
    }
    float2 rr;
    rr.x = ax;
    rr.y = ay;
    ((float2*)(out + (size_t)d * HID))[lane] = rr;
}

extern "C" void kernel_launch(void* const* d_in, const int* in_sizes, int n_in,
                              void* d_out, int out_size, void* d_ws, size_t ws_size,
                              hipStream_t stream) {
    const float* x = (const float*)d_in[0];
    const int* ei = (const int*)d_in[1];
    const float* ew = (const float*)d_in[2];
    const float* W1 = (const float*)d_in[3];
    const float* b1 = (const float*)d_in[4];
    const float* W2 = (const float*)d_in[5];
    const float* b2 = (const float*)d_in[6];
    const int* src = ei;
    const int* dst = ei + NE;
    float* out = (float*)d_out;

    // Workspace layout (lifetime-aliased; high-water mark 42,795,136 B):
    //   h       @ 0          32 MB  persistent (first written by gemm1)
    //     pos_rep aliases h[0..2MB] — dead after k_scatter, before gemm1
    //   edata   @ 33,554,432  8 MB  persistent (first written by k_scatter)
    //     tot  aliases edata[0..256KB]   — dead before k_scatter
    //     bsum aliases edata[256KB..+1KB] — dead before k_scatter
    //   row_ptr @ 41,943,040  (64K+1 ints, persistent)
    //   dinv    @ 42,205,312  (256 KB, persistent)
    //   bp1     @ 42,467,456  (256 KB, persistent)
    //   bp2     @ 42,729,600  ( 64 KB, persistent)
    char* ws = (char*)d_ws;
    float* h       = (float*)(ws + 0);
    int*   pos_rep = (int*)(ws + 0);
    uint2* edata   = (uint2*)(ws + 33554432);
    int*   tot     = (int*)(ws + 33554432);
    int*   bsum    = (int*)(ws + 33816576);
    int*   row_ptr = (int*)(ws + 41943040);
    float* dinv    = (float*)(ws + 42205312);
    unsigned short* bp1 = (unsigned short*)(ws + 42467456);
    unsigned short* bp2 = (unsigned short*)(ws + 42729600);

    // CSR build (atomic-light): replicated hist -> scan -> scatter -> deg/dinv -> coef
    k_zero_cnt<<<NREP * NN / 256, 256, 0, stream>>>(pos_rep);
    k_hist<<<NE / 256, 256, 0, stream>>>(dst, pos_rep);
    k_rowptr_pre<<<NN / 256, 256, 0, stream>>>(pos_rep, tot);
    k_scan_block<<<256, 256, 0, stream>>>(tot, row_ptr, bsum);
    k_scan_bsum<<<1, 256, 0, stream>>>(bsum);
    k_scan_add<<<256, 256, 0, stream>>>(row_ptr, bsum, pos_rep);
    k_scatter<<<NE / 256, 256, 0, stream>>>(src, dst, ew, pos_rep, edata);
    k_deg_dinv<<<NN / 256, 256, 0, stream>>>(row_ptr, edata, dinv);
    k_coef<<<NE / 256, 256, 0, stream>>>(dinv, edata);
    k_prep_pack<INDIM><<<(INDIM / 16) * 8 * 64 / 256, 256, 0, stream>>>(W1, bp1);
    k_prep_pack<HID><<<(HID / 16) * 8 * 64 / 256, 256, 0, stream>>>(W2, bp2);

    // layer 1: h = x @ W1 ; a1 = relu(agg(h) + b1) -> d_out
    k_gemm_mfma<INDIM><<<NN / 64, 256, 0, stream>>>(x, bp1, h);
    k_agg<true><<<NN / 4, 256, 0, stream>>>(h, dinv, row_ptr, edata, b1, out);

    // layer 2: h2 = a1 @ W2 -> h ; z = agg(h2) + b2 -> d_out
    k_gemm_mfma<HID><<<NN / 64, 256, 0, stream>>>(out, bp2, h);
    k_agg<false><<<NN / 4, 256, 0, stream>>>(h, dinv, row_ptr, edata, b2, out);
}

// Round 7
// 307.484 us; speedup vs baseline: 1.7493x; 1.1773x over previous
//
#include <hip/hip_runtime.h>

#define NN 65536
#define NE 1048576
#define INDIM 512
#define HID 128
#define NREP 8

typedef __attribute__((ext_vector_type(8))) short bf16x8;
typedef __attribute__((ext_vector_type(16))) float f32x16;

// ---------------- zero the replicated histogram ----------------
__global__ void k_zero_cnt(int* pos_rep) {
    int i = blockIdx.x * 256 + threadIdx.x;
    pos_rep[i] = 0;  // grid sized exactly NREP*NN
}

// ---------------- replicated int histogram over dst (into pos_rep) ----------------
__global__ void k_hist(const int* __restrict__ dst, int* pos_rep) {
    int e = blockIdx.x * 256 + threadIdx.x;
    int r = blockIdx.x & (NREP - 1);
    if (e < NE) atomicAdd(&pos_rep[r * NN + dst[e]], 1);
}

// ---------------- per-node replica prefix (in place) + totals ----------------
__global__ void k_rowptr_pre(int* pos_rep, int* tot) {
    int i = blockIdx.x * 256 + threadIdx.x;  // node
    int s = 0;
#pragma unroll
    for (int r = 0; r < NREP; r++) {
        int c = pos_rep[r * NN + i];
        pos_rep[r * NN + i] = s;  // relative offset within node segment
        s += c;
    }
    tot[i] = s;
}

// ---------------- two-level exclusive scan of tot -> row_ptr ----------------
__global__ void k_scan_block(const int* __restrict__ tot, int* row_ptr, int* bsum) {
    __shared__ int tmp[256];
    int i = blockIdx.x * 256 + threadIdx.x;
    int v = tot[i];
    tmp[threadIdx.x] = v;
    __syncthreads();
    for (int off = 1; off < 256; off <<= 1) {
        int t = (threadIdx.x >= off) ? tmp[threadIdx.x - off] : 0;
        __syncthreads();
        tmp[threadIdx.x] += t;
        __syncthreads();
    }
    row_ptr[i] = tmp[threadIdx.x] - v;   // exclusive
    if (threadIdx.x == 255) bsum[blockIdx.x] = tmp[255];
}

__global__ void k_scan_bsum(int* bsum) {
    __shared__ int tmp[256];
    int v = bsum[threadIdx.x];
    tmp[threadIdx.x] = v;
    __syncthreads();
    for (int off = 1; off < 256; off <<= 1) {
        int t = (threadIdx.x >= off) ? tmp[threadIdx.x - off] : 0;
        __syncthreads();
        tmp[threadIdx.x] += t;
        __syncthreads();
    }
    bsum[threadIdx.x] = tmp[threadIdx.x] - v; // exclusive block offsets
}

__global__ void k_scan_add(int* row_ptr, const int* __restrict__ bsum, int* pos_rep) {
    int i = blockIdx.x * 256 + threadIdx.x;
    int rp = row_ptr[i] + bsum[blockIdx.x];
    row_ptr[i] = rp;
#pragma unroll
    for (int r = 0; r < NREP; r++) pos_rep[r * NN + i] += rp;  // absolute cursors
    if (i == 0) row_ptr[NN] = NE;
}

// ---------------- scatter edges into dst-sorted order ----------------
__global__ void k_scatter(const int* __restrict__ src, const int* __restrict__ dst,
                          const float* __restrict__ ew,
                          int* pos_rep, uint2* __restrict__ edata) {
    int e = blockIdx.x * 256 + threadIdx.x;
    int r = blockIdx.x & (NREP - 1);
    if (e < NE) {
        int d = dst[e];
        int p = atomicAdd(&pos_rep[r * NN + d], 1);
        uint2 u;
        u.x = (unsigned)src[e];
        u.y = __float_as_uint(ew[e]);
        edata[p] = u;
    }
}

// ---------------- deg from CSR (no atomics) + dinv ----------------
__global__ void k_deg_dinv(const int* __restrict__ row_ptr, const uint2* __restrict__ edata,
                           float* __restrict__ dinv) {
    int d = blockIdx.x * 256 + threadIdx.x;  // one thread per node
    int beg = row_ptr[d], end = row_ptr[d + 1];
    float deg = 1.0f;  // self-loop weight
    for (int e = beg; e < end; ++e) deg += __uint_as_float(edata[e].y);
    dinv[d] = (deg > 0.f) ? rsqrtf(deg) : 0.f;
}

// ---------------- fold dinv[src] into edge weight ----------------
__global__ void k_coef(const float* __restrict__ dinv, uint2* edata) {
    int e = blockIdx.x * 256 + threadIdx.x;
    if (e < NE) {
        uint2 u = edata[e];
        float c = dinv[u.x] * __uint_as_float(u.y);
        u.y = __float_as_uint(c);
        edata[e] = u;
    }
}

// ---------------- W prep: f32 [K][128] -> MFMA-fragment-packed split-bf16 ----------------
// Layout: P[(((k0*4 + n)*2 + h)*64 + lane)*8 + j]  (16B granule per lane-fragment)
template <int K>
__global__ void k_prep_pack(const float* __restrict__ W, unsigned short* __restrict__ P) {
    int t = blockIdx.x * 256 + threadIdx.x;
    int l = t & 63;
    int h = (t >> 6) & 1;
    int n = (t >> 7) & 3;
    int k0 = t >> 9;
    if (k0 >= K / 16) return;
    int colg = n * 32 + (l & 31);
    int kbase = k0 * 16 + (l >> 5) * 8;
    bf16x8 v;
#pragma unroll
    for (int j = 0; j < 8; j++) {
        float f = W[(size_t)(kbase + j) * 128 + colg];
        unsigned b = __float_as_uint(f);
        if (h == 0) {
            v[j] = (short)(b >> 16);
        } else {
            float lf = f - __uint_as_float(b & 0xFFFF0000u);
            v[j] = (short)(__float_as_uint(lf) >> 16);
        }
    }
    *(bf16x8*)(P + (size_t)t * 8) = v;
}

// ---------------- split-bf16 MFMA GEMM: C[M,128] = A[M,K] @ W[K,128], C in bf16 ----------------
__device__ __forceinline__ void split8(const float4& a0, const float4& a1,
                                       bf16x8& hi, bf16x8& lo) {
    float f[8] = {a0.x, a0.y, a0.z, a0.w, a1.x, a1.y, a1.z, a1.w};
#pragma unroll
    for (int i = 0; i < 8; i++) {
        unsigned b = __float_as_uint(f[i]);
        unsigned hb = b & 0xFFFF0000u;
        float lf = f[i] - __uint_as_float(hb);
        hi[i] = (short)(hb >> 16);
        lo[i] = (short)(__float_as_uint(lf) >> 16);
    }
}

__device__ __forceinline__ unsigned short f2bf_rne(float v) {
    unsigned u = __float_as_uint(v);
    unsigned r = (u + 0x7FFFu + ((u >> 16) & 1u)) >> 16;
    return (unsigned short)r;
}

// Stage one BK=32 chunk into LDS via global_load_lds (width 16, linear dest).
template <int K>
__device__ __forceinline__ void stage_chunk(const float* __restrict__ A, int rowbase,
                                            const unsigned short* __restrict__ Bp,
                                            int c, int tid, float* As, unsigned short* Bs) {
    const int w = tid >> 6;
    // A: 8KB = 2 calls x 256 threads x 16B
#pragma unroll
    for (int q = 0; q < 2; ++q) {
        int lh = (tid >> 7) & 1;
        int row = (tid >> 1) & 63;
        int g = (tid & 1) ^ ((row >> 2) & 1);
        const float* src = A + (size_t)(rowbase + row) * K + c * 32 + q * 16 + lh * 8 + g * 4;
        char* dst = (char*)As + (size_t)(q * 256 + w * 64) * 16;
        __builtin_amdgcn_global_load_lds((const __attribute__((address_space(1))) void*)src,
                                         (__attribute__((address_space(3))) void*)dst, 16, 0, 0);
    }
    // B: 16KB = 4 calls (identity copy)
    const char* bsrc0 = (const char*)Bp + (size_t)c * 16384;
#pragma unroll
    for (int q = 0; q < 4; ++q) {
        const char* src = bsrc0 + (size_t)(q * 256 + tid) * 16;
        char* dst = (char*)Bs + (size_t)(q * 256 + w * 64) * 16;
        __builtin_amdgcn_global_load_lds((const __attribute__((address_space(1))) void*)src,
                                         (__attribute__((address_space(3))) void*)dst, 16, 0, 0);
    }
}

// Block: 64 rows x 128 cols, 4 waves (2 row-groups x 2 col-groups), wave tile 32x64.
template <int K>
__global__ __launch_bounds__(256, 4) void k_gemm_mfma(const float* __restrict__ A,
                                                      const unsigned short* __restrict__ Bp,
                                                      unsigned short* __restrict__ Cb) {
    constexpr int NC = K / 32;
    __shared__ __align__(16) float As[2048];            // 8KB
    __shared__ __align__(16) unsigned short Bs[8192];   // 16KB
    const int tid = threadIdx.x;
    const int w = tid >> 6;
    const int lane = tid & 63;
    const int l31 = lane & 31;
    const int lhalf = lane >> 5;
    const int rowbase = blockIdx.x * 64;
    const int ncol = (w & 1) * 2;          // col-group: tiles ncol, ncol+1
    const int r = (w >> 1) * 32 + l31;     // row within 64-row tile
    const int xr = (l31 >> 2) & 1;

    f32x16 acc[2] = {};

    stage_chunk<K>(A, rowbase, Bp, 0, tid, As, Bs);

    for (int c = 0; c < NC; ++c) {
        __syncthreads();  // staged chunk visible (compiler drains vmcnt before barrier)
#pragma unroll
        for (int kk = 0; kk < 2; ++kk) {
            int bg = ((kk * 2 + lhalf) * 64 + r) * 2;
            float4 aa = *(const float4*)&As[(size_t)(bg + xr) * 4];        // k+0..3
            float4 ab = *(const float4*)&As[(size_t)(bg + (1 ^ xr)) * 4];  // k+4..7
            bf16x8 ahi, alo;
            split8(aa, ab, ahi, alo);
#pragma unroll
            for (int n = 0; n < 2; ++n) {
                int f = (ncol + n) * 2;
                bf16x8 bhi = *(const bf16x8*)&Bs[(size_t)((kk * 8 + f) * 64 + lane) * 8];
                bf16x8 blo = *(const bf16x8*)&Bs[(size_t)((kk * 8 + f + 1) * 64 + lane) * 8];
                acc[n] = __builtin_amdgcn_mfma_f32_32x32x16_bf16(ahi, bhi, acc[n], 0, 0, 0);
                acc[n] = __builtin_amdgcn_mfma_f32_32x32x16_bf16(ahi, blo, acc[n], 0, 0, 0);
                acc[n] = __builtin_amdgcn_mfma_f32_32x32x16_bf16(alo, bhi, acc[n], 0, 0, 0);
            }
        }
        __syncthreads();  // all waves done reading before restaging
        if (c + 1 < NC) stage_chunk<K>(A, rowbase, Bp, c + 1, tid, As, Bs);
    }

    const int rbase = rowbase + (w >> 1) * 32 + 4 * lhalf;
#pragma unroll
    for (int n = 0; n < 2; ++n) {
        const int col = (ncol + n) * 32 + l31;
#pragma unroll
        for (int rr = 0; rr < 16; ++rr) {
            int rout = rbase + (rr & 3) + 8 * (rr >> 2);
            Cb[(size_t)rout * HID + col] = f2bf_rne(acc[n][rr]);
        }
    }
}

// ---------------- aggregation: out[d] = di*(sum c*h[s]) + di^2*h[d] + b (h in bf16) ----------------
__device__ __forceinline__ float2 up2(unsigned u) {
    float2 r;
    r.x = __uint_as_float(u << 16);
    r.y = __uint_as_float(u & 0xFFFF0000u);
    return r;
}

template <bool RELU>
__global__ __launch_bounds__(256) void k_agg(const unsigned short* __restrict__ hb,
                                             const float* __restrict__ dinv,
                                             const int* __restrict__ row_ptr,
                                             const uint2* __restrict__ edata,
                                             const float* __restrict__ bias,
                                             float* __restrict__ out) {
    int d = (blockIdx.x * blockDim.x + threadIdx.x) >> 6;  // one wave per node
    int lane = threadIdx.x & 63;
    if (d >= NN) return;
    float di = dinv[d];
    float2 hv = up2(((const unsigned*)(hb + (size_t)d * HID))[lane]);
    int beg = row_ptr[d], end = row_ptr[d + 1];
    float ex = 0.f, ey = 0.f;
    int e = beg;
    for (; e + 3 < end; e += 4) {
        uint2 u0 = edata[e], u1 = edata[e + 1], u2 = edata[e + 2], u3 = edata[e + 3];
        unsigned g0 = ((const unsigned*)(hb + (size_t)u0.x * HID))[lane];
        unsigned g1 = ((const unsigned*)(hb + (size_t)u1.x * HID))[lane];
        unsigned g2 = ((const unsigned*)(hb + (size_t)u2.x * HID))[lane];
        unsigned g3 = ((const unsigned*)(hb + (size_t)u3.x * HID))[lane];
        float2 v0 = up2(g0), v1 = up2(g1), v2 = up2(g2), v3 = up2(g3);
        float c0 = __uint_as_float(u0.y), c1 = __uint_as_float(u1.y);
        float c2 = __uint_as_float(u2.y), c3 = __uint_as_float(u3.y);
        ex += c0 * v0.x; ey += c0 * v0.y;
        ex += c1 * v1.x; ey += c1 * v1.y;
        ex += c2 * v2.x; ey += c2 * v2.y;
        ex += c3 * v3.x; ey += c3 * v3.y;
    }
    for (; e < end; ++e) {
        uint2 u = edata[e];
        float2 v = up2(((const unsigned*)(hb + (size_t)u.x * HID))[lane]);
        float c = __uint_as_float(u.y);
        ex += c * v.x; ey += c * v.y;
    }
    float2 bv = ((const float2*)bias)[lane];
    float selfc = di * di;
    float ax = di * ex + selfc * hv.x + bv.x;
    float ay = di * ey + selfc * hv.y + bv.y;
    if (RELU) {
        ax = fmaxf(ax, 0.f);
        ay = fmaxf(ay, 0.f);
    }
    float2 rr;
    rr.x = ax;
    rr.y = ay;
    ((float2*)(out + (size_t)d * HID))[lane] = rr;
}

extern "C" void kernel_launch(void* const* d_in, const int* in_sizes, int n_in,
                              void* d_out, int out_size, void* d_ws, size_t ws_size,
                              hipStream_t stream) {
    const float* x = (const float*)d_in[0];
    const int* ei = (const int*)d_in[1];
    const float* ew = (const float*)d_in[2];
    const float* W1 = (const float*)d_in[3];
    const float* b1 = (const float*)d_in[4];
    const float* W2 = (const float*)d_in[5];
    const float* b2 = (const float*)d_in[6];
    const int* src = ei;
    const int* dst = ei + NE;
    float* out = (float*)d_out;

    // Workspace layout (lifetime-aliased; high-water mark ~26.3 MB):
    //   hb      @ 0          16 MB bf16 h (first written by gemm1)
    //     pos_rep aliases hb[0..2MB] — dead after k_scatter, before gemm1
    //   edata   @ 16,777,216  8 MB (first written by k_scatter)
    //     tot  aliases edata[0..256KB]    — dead before k_scatter
    //     bsum aliases edata[256KB..+1KB] — dead before k_scatter
    //   row_ptr @ 25,165,824 (64K+1 ints)
    //   dinv    @ 25,690,112 (256 KB)
    //   bp1     @ 25,952,256 (256 KB)
    //   bp2     @ 26,214,400 ( 64 KB)
    char* ws = (char*)d_ws;
    unsigned short* hb = (unsigned short*)(ws + 0);
    int*   pos_rep = (int*)(ws + 0);
    uint2* edata   = (uint2*)(ws + 16777216);
    int*   tot     = (int*)(ws + 16777216);
    int*   bsum    = (int*)(ws + 17039360);
    int*   row_ptr = (int*)(ws + 25165824);
    float* dinv    = (float*)(ws + 25690112);
    unsigned short* bp1 = (unsigned short*)(ws + 25952256);
    unsigned short* bp2 = (unsigned short*)(ws + 26214400);

    // CSR build (atomic-light): replicated hist -> scan -> scatter -> deg/dinv -> coef
    k_zero_cnt<<<NREP * NN / 256, 256, 0, stream>>>(pos_rep);
    k_hist<<<NE / 256, 256, 0, stream>>>(dst, pos_rep);
    k_rowptr_pre<<<NN / 256, 256, 0, stream>>>(pos_rep, tot);
    k_scan_block<<<256, 256, 0, stream>>>(tot, row_ptr, bsum);
    k_scan_bsum<<<1, 256, 0, stream>>>(bsum);
    k_scan_add<<<256, 256, 0, stream>>>(row_ptr, bsum, pos_rep);
    k_scatter<<<NE / 256, 256, 0, stream>>>(src, dst, ew, pos_rep, edata);
    k_deg_dinv<<<NN / 256, 256, 0, stream>>>(row_ptr, edata, dinv);
    k_coef<<<NE / 256, 256, 0, stream>>>(dinv, edata);
    k_prep_pack<INDIM><<<(INDIM / 16) * 8 * 64 / 256, 256, 0, stream>>>(W1, bp1);
    k_prep_pack<HID><<<(HID / 16) * 8 * 64 / 256, 256, 0, stream>>>(W2, bp2);

    // layer 1: hb = bf16(x @ W1) ; a1 = relu(agg(hb) + b1) -> d_out (f32)
    k_gemm_mfma<INDIM><<<NN / 64, 256, 0, stream>>>(x, bp1, hb);
    k_agg<true><<<NN / 4, 256, 0, stream>>>(hb, dinv, row_ptr, edata, b1, out);

    // layer 2: hb = bf16(a1 @ W2) ; z = agg(hb) + b2 -> d_out (f32)
    k_gemm_mfma<HID><<<NN / 64, 256, 0, stream>>>(out, bp2, hb);
    k_agg<false><<<NN / 4, 256, 0, stream>>>(hb, dinv, row_ptr, edata, b2, out);
}

// Round 8
// 252.945 us; speedup vs baseline: 2.1264x; 1.2156x over previous
//
#include <hip/hip_runtime.h>

#define NN 65536
#define NE 1048576
#define INDIM 512
#define HID 128
#define NB 4096  // edge blocks (NE/256)

typedef __attribute__((ext_vector_type(8))) short bf16x8;
typedef __attribute__((ext_vector_type(16))) float f32x16;

// ---------------- pass 1: per-block LDS histogram over lo8(dst) ----------------
__global__ void k_h1(const int* __restrict__ dst, int* __restrict__ ghist) {
    __shared__ int hcnt[256];
    hcnt[threadIdx.x] = 0;
    __syncthreads();
    int e = blockIdx.x * 256 + threadIdx.x;
    atomicAdd(&hcnt[dst[e] & 255], 1);  // LDS atomic
    __syncthreads();
    ghist[threadIdx.x * NB + blockIdx.x] = hcnt[threadIdx.x];  // bin-major
}

// ---------------- generic 256-wide in-place exclusive scan level ----------------
__global__ void k_scan_ex(int* data, int* bsum, int n) {
    __shared__ int tmp[256];
    int i = blockIdx.x * 256 + threadIdx.x;
    int v = (i < n) ? data[i] : 0;
    tmp[threadIdx.x] = v;
    __syncthreads();
    for (int off = 1; off < 256; off <<= 1) {
        int t = (threadIdx.x >= off) ? tmp[threadIdx.x - off] : 0;
        __syncthreads();
        tmp[threadIdx.x] += t;
        __syncthreads();
    }
    if (i < n) data[i] = tmp[threadIdx.x] - v;  // exclusive
    if (threadIdx.x == 255 && bsum) bsum[blockIdx.x] = tmp[255];
}

__global__ void k_addback(int* data, const int* __restrict__ bsum) {
    int i = blockIdx.x * 256 + threadIdx.x;
    data[i] += bsum[blockIdx.x];
}

// ---------------- pass 1 scatter: group edges by lo8(dst), LDS cursors only ----------------
__global__ void k_s1(const int* __restrict__ src, const int* __restrict__ dst,
                     const float* __restrict__ ew, const int* __restrict__ ghist,
                     int* __restrict__ e1src, float* __restrict__ e1ew,
                     int* __restrict__ e1dst) {
    __shared__ int cur[256];
    cur[threadIdx.x] = ghist[threadIdx.x * NB + blockIdx.x];  // scanned global base
    __syncthreads();
    int e = blockIdx.x * 256 + threadIdx.x;
    int d = dst[e];
    int p = atomicAdd(&cur[d & 255], 1);  // LDS atomic; region is block-private
    e1src[p] = src[e];
    e1ew[p] = ew[e];
    e1dst[p] = d;
}

// ---------------- pass 2: one block per bin -> final dst-grouped edata + rows + dinv ----------------
__global__ void k_s2(const int* __restrict__ ghist, const int* __restrict__ e1src,
                     const float* __restrict__ e1ew, const int* __restrict__ e1dst,
                     uint2* __restrict__ edata, int* __restrict__ row_beg,
                     int* __restrict__ row_end, float* __restrict__ dinv) {
    __shared__ int cnt[256];
    __shared__ float degs[256];
    __shared__ int tmp[256];
    __shared__ int curx[256];
    const int bin = blockIdx.x;
    const int t = threadIdx.x;
    cnt[t] = 0;
    degs[t] = 0.f;
    __syncthreads();
    const int binstart = ghist[bin * NB];
    const int binend = (bin == 255) ? NE : ghist[(bin + 1) * NB];
    for (int i = binstart + t; i < binend; i += 256) {
        int j = e1dst[i] >> 8;
        atomicAdd(&cnt[j], 1);           // LDS
        atomicAdd(&degs[j], e1ew[i]);    // LDS float
    }
    __syncthreads();
    // exclusive scan of cnt
    int v = cnt[t];
    tmp[t] = v;
    __syncthreads();
    for (int off = 1; off < 256; off <<= 1) {
        int u = (t >= off) ? tmp[t - off] : 0;
        __syncthreads();
        tmp[t] += u;
        __syncthreads();
    }
    int offt = tmp[t] - v;
    int d = (t << 8) | bin;
    int beg = binstart + offt;
    row_beg[d] = beg;
    row_end[d] = beg + v;
    dinv[d] = rsqrtf(1.0f + degs[t]);  // deg >= 1 (self-loop), ew >= 0
    curx[t] = beg;
    __syncthreads();
    for (int i = binstart + t; i < binend; i += 256) {
        int dd = e1dst[i];
        int p = atomicAdd(&curx[dd >> 8], 1);  // LDS; same-dst edges stay contiguous
        edata[p] = make_uint2((unsigned)e1src[i], __float_as_uint(e1ew[i]));
    }
}

// ---------------- fold dinv[src] into edge weight ----------------
__global__ void k_coef(const float* __restrict__ dinv, uint2* edata) {
    int e = blockIdx.x * 256 + threadIdx.x;
    uint2 u = edata[e];
    float c = dinv[u.x] * __uint_as_float(u.y);
    u.y = __float_as_uint(c);
    edata[e] = u;
}

// ---------------- W prep: f32 [K][128] -> MFMA-fragment-packed split-bf16 ----------------
template <int K>
__global__ void k_prep_pack(const float* __restrict__ W, unsigned short* __restrict__ P) {
    int t = blockIdx.x * 256 + threadIdx.x;
    int l = t & 63;
    int h = (t >> 6) & 1;
    int n = (t >> 7) & 3;
    int k0 = t >> 9;
    if (k0 >= K / 16) return;
    int colg = n * 32 + (l & 31);
    int kbase = k0 * 16 + (l >> 5) * 8;
    bf16x8 v;
#pragma unroll
    for (int j = 0; j < 8; j++) {
        float f = W[(size_t)(kbase + j) * 128 + colg];
        unsigned b = __float_as_uint(f);
        if (h == 0) {
            v[j] = (short)(b >> 16);
        } else {
            float lf = f - __uint_as_float(b & 0xFFFF0000u);
            v[j] = (short)(__float_as_uint(lf) >> 16);
        }
    }
    *(bf16x8*)(P + (size_t)t * 8) = v;
}

// ---------------- split-bf16 MFMA GEMM: C[M,128] = A[M,K] @ W[K,128], C in bf16 ----------------
__device__ __forceinline__ void split8(const float4& a0, const float4& a1,
                                       bf16x8& hi, bf16x8& lo) {
    float f[8] = {a0.x, a0.y, a0.z, a0.w, a1.x, a1.y, a1.z, a1.w};
#pragma unroll
    for (int i = 0; i < 8; i++) {
        unsigned b = __float_as_uint(f[i]);
        unsigned hb = b & 0xFFFF0000u;
        float lf = f[i] - __uint_as_float(hb);
        hi[i] = (short)(hb >> 16);
        lo[i] = (short)(__float_as_uint(lf) >> 16);
    }
}

__device__ __forceinline__ unsigned short f2bf_rne(float v) {
    unsigned u = __float_as_uint(v);
    unsigned r = (u + 0x7FFFu + ((u >> 16) & 1u)) >> 16;
    return (unsigned short)r;
}

template <int K>
__device__ __forceinline__ void stage_chunk(const float* __restrict__ A, int rowbase,
                                            const unsigned short* __restrict__ Bp,
                                            int c, int tid, float* As, unsigned short* Bs) {
    const int w = tid >> 6;
#pragma unroll
    for (int q = 0; q < 2; ++q) {
        int lh = (tid >> 7) & 1;
        int row = (tid >> 1) & 63;
        int g = (tid & 1) ^ ((row >> 2) & 1);
        const float* src = A + (size_t)(rowbase + row) * K + c * 32 + q * 16 + lh * 8 + g * 4;
        char* dst = (char*)As + (size_t)(q * 256 + w * 64) * 16;
        __builtin_amdgcn_global_load_lds((const __attribute__((address_space(1))) void*)src,
                                         (__attribute__((address_space(3))) void*)dst, 16, 0, 0);
    }
    const char* bsrc0 = (const char*)Bp + (size_t)c * 16384;
#pragma unroll
    for (int q = 0; q < 4; ++q) {
        const char* src = bsrc0 + (size_t)(q * 256 + tid) * 16;
        char* dst = (char*)Bs + (size_t)(q * 256 + w * 64) * 16;
        __builtin_amdgcn_global_load_lds((const __attribute__((address_space(1))) void*)src,
                                         (__attribute__((address_space(3))) void*)dst, 16, 0, 0);
    }
}

template <int K>
__global__ __launch_bounds__(256, 4) void k_gemm_mfma(const float* __restrict__ A,
                                                      const unsigned short* __restrict__ Bp,
                                                      unsigned short* __restrict__ Cb) {
    constexpr int NC = K / 32;
    __shared__ __align__(16) float As[2048];            // 8KB
    __shared__ __align__(16) unsigned short Bs[8192];   // 16KB
    const int tid = threadIdx.x;
    const int w = tid >> 6;
    const int lane = tid & 63;
    const int l31 = lane & 31;
    const int lhalf = lane >> 5;
    const int rowbase = blockIdx.x * 64;
    const int ncol = (w & 1) * 2;
    const int r = (w >> 1) * 32 + l31;
    const int xr = (l31 >> 2) & 1;

    f32x16 acc[2] = {};

    stage_chunk<K>(A, rowbase, Bp, 0, tid, As, Bs);

    for (int c = 0; c < NC; ++c) {
        __syncthreads();
#pragma unroll
        for (int kk = 0; kk < 2; ++kk) {
            int bg = ((kk * 2 + lhalf) * 64 + r) * 2;
            float4 aa = *(const float4*)&As[(size_t)(bg + xr) * 4];
            float4 ab = *(const float4*)&As[(size_t)(bg + (1 ^ xr)) * 4];
            bf16x8 ahi, alo;
            split8(aa, ab, ahi, alo);
#pragma unroll
            for (int n = 0; n < 2; ++n) {
                int f = (ncol + n) * 2;
                bf16x8 bhi = *(const bf16x8*)&Bs[(size_t)((kk * 8 + f) * 64 + lane) * 8];
                bf16x8 blo = *(const bf16x8*)&Bs[(size_t)((kk * 8 + f + 1) * 64 + lane) * 8];
                acc[n] = __builtin_amdgcn_mfma_f32_32x32x16_bf16(ahi, bhi, acc[n], 0, 0, 0);
                acc[n] = __builtin_amdgcn_mfma_f32_32x32x16_bf16(ahi, blo, acc[n], 0, 0, 0);
                acc[n] = __builtin_amdgcn_mfma_f32_32x32x16_bf16(alo, bhi, acc[n], 0, 0, 0);
            }
        }
        __syncthreads();
        if (c + 1 < NC) stage_chunk<K>(A, rowbase, Bp, c + 1, tid, As, Bs);
    }

    const int rbase = rowbase + (w >> 1) * 32 + 4 * lhalf;
#pragma unroll
    for (int n = 0; n < 2; ++n) {
        const int col = (ncol + n) * 32 + l31;
#pragma unroll
        for (int rr = 0; rr < 16; ++rr) {
            int rout = rbase + (rr & 3) + 8 * (rr >> 2);
            Cb[(size_t)rout * HID + col] = f2bf_rne(acc[n][rr]);
        }
    }
}

// ---------------- aggregation: out[d] = di*(sum c*h[s]) + di^2*h[d] + b (h in bf16) ----------------
__device__ __forceinline__ float2 up2(unsigned u) {
    float2 r;
    r.x = __uint_as_float(u << 16);
    r.y = __uint_as_float(u & 0xFFFF0000u);
    return r;
}

template <bool RELU>
__global__ __launch_bounds__(256) void k_agg(const unsigned short* __restrict__ hb,
                                             const float* __restrict__ dinv,
                                             const int* __restrict__ row_beg,
                                             const int* __restrict__ row_end,
                                             const uint2* __restrict__ edata,
                                             const float* __restrict__ bias,
                                             float* __restrict__ out) {
    int d = (blockIdx.x * blockDim.x + threadIdx.x) >> 6;  // one wave per node
    int lane = threadIdx.x & 63;
    float di = dinv[d];
    float2 hv = up2(((const unsigned*)(hb + (size_t)d * HID))[lane]);
    int beg = row_beg[d], end = row_end[d];
    float ex = 0.f, ey = 0.f;
    int e = beg;
    for (; e + 7 < end; e += 8) {
        uint2 u[8];
        unsigned g[8];
#pragma unroll
        for (int q = 0; q < 8; q++) u[q] = edata[e + q];
#pragma unroll
        for (int q = 0; q < 8; q++) g[q] = ((const unsigned*)(hb + (size_t)u[q].x * HID))[lane];
#pragma unroll
        for (int q = 0; q < 8; q++) {
            float2 vv = up2(g[q]);
            float c = __uint_as_float(u[q].y);
            ex += c * vv.x;
            ey += c * vv.y;
        }
    }
    for (; e < end; ++e) {
        uint2 u = edata[e];
        float2 v = up2(((const unsigned*)(hb + (size_t)u.x * HID))[lane]);
        float c = __uint_as_float(u.y);
        ex += c * v.x;
        ey += c * v.y;
    }
    float2 bv = ((const float2*)bias)[lane];
    float selfc = di * di;
    float ax = di * ex + selfc * hv.x + bv.x;
    float ay = di * ey + selfc * hv.y + bv.y;
    if (RELU) {
        ax = fmaxf(ax, 0.f);
        ay = fmaxf(ay, 0.f);
    }
    float2 rr;
    rr.x = ax;
    rr.y = ay;
    ((float2*)(out + (size_t)d * HID))[lane] = rr;
}

extern "C" void kernel_launch(void* const* d_in, const int* in_sizes, int n_in,
                              void* d_out, int out_size, void* d_ws, size_t ws_size,
                              hipStream_t stream) {
    const float* x = (const float*)d_in[0];
    const int* ei = (const int*)d_in[1];
    const float* ew = (const float*)d_in[2];
    const float* W1 = (const float*)d_in[3];
    const float* b1 = (const float*)d_in[4];
    const float* W2 = (const float*)d_in[5];
    const float* b2 = (const float*)d_in[6];
    const int* src = ei;
    const int* dst = ei + NE;
    float* out = (float*)d_out;

    // Workspace layout — fully disjoint, high-water 43,073,536 B (< 43,091,200 proven):
    char* ws = (char*)d_ws;
    unsigned short* hb = (unsigned short*)(ws + 0);          // 16 MB bf16 h
    uint2* edata   = (uint2*)(ws + 16777216);                //  8 MB final grouped edges
    int*   ghist   = (int*)(ws + 25165824);                  //  4 MB bin-major histogram
    int*   e1src   = (int*)(ws + 29360128);                  //  4 MB pass-1 src
    float* e1ew    = (float*)(ws + 33554432);                //  4 MB pass-1 ew
    int*   e1dst   = (int*)(ws + 37748736);                  //  4 MB pass-1 dst
    int*   bsum1   = (int*)(ws + 41943040);                  // 16 KB
    int*   bsum2   = (int*)(ws + 41959424);                  //  1 KB
    int*   row_beg = (int*)(ws + 41960448);                  // 256 KB
    int*   row_end = (int*)(ws + 42222592);                  // 256 KB
    float* dinv    = (float*)(ws + 42484736);                // 256 KB
    unsigned short* bp1 = (unsigned short*)(ws + 42746880);  // 256 KB
    unsigned short* bp2 = (unsigned short*)(ws + 43009024);  //  64 KB

    // CSR build — zero global atomics:
    k_h1<<<NB, 256, 0, stream>>>(dst, ghist);
    k_scan_ex<<<NB, 256, 0, stream>>>(ghist, bsum1, 256 * NB);
    k_scan_ex<<<16, 256, 0, stream>>>(bsum1, bsum2, NB);
    k_scan_ex<<<1, 256, 0, stream>>>(bsum2, nullptr, 16);
    k_addback<<<16, 256, 0, stream>>>(bsum1, bsum2);
    k_addback<<<NB, 256, 0, stream>>>(ghist, bsum1);
    k_s1<<<NB, 256, 0, stream>>>(src, dst, ew, ghist, e1src, e1ew, e1dst);
    k_s2<<<256, 256, 0, stream>>>(ghist, e1src, e1ew, e1dst, edata, row_beg, row_end, dinv);
    k_coef<<<NB, 256, 0, stream>>>(dinv, edata);
    k_prep_pack<INDIM><<<(INDIM / 16) * 8 * 64 / 256, 256, 0, stream>>>(W1, bp1);
    k_prep_pack<HID><<<(HID / 16) * 8 * 64 / 256, 256, 0, stream>>>(W2, bp2);

    // layer 1: hb = bf16(x @ W1) ; a1 = relu(agg(hb) + b1) -> d_out (f32)
    k_gemm_mfma<INDIM><<<NN / 64, 256, 0, stream>>>(x, bp1, hb);
    k_agg<true><<<NN / 4, 256, 0, stream>>>(hb, dinv, row_beg, row_end, edata, b1, out);

    // layer 2: hb = bf16(a1 @ W2) ; z = agg(hb) + b2 -> d_out (f32)
    k_gemm_mfma<HID><<<NN / 64, 256, 0, stream>>>(out, bp2, hb);
    k_agg<false><<<NN / 4, 256, 0, stream>>>(hb, dinv, row_beg, row_end, edata, b2, out);
}